// Round 4
// baseline (292.460 us; speedup 1.0000x reference)
//
#include <hip/hip_runtime.h>
#include <hip/hip_bf16.h>
#include <math.h>

#define HDIM 1024
#define SEQ  2048
#define BATCH 2
#define NHEAD 16
#define HEADD 64

typedef short bf16x8 __attribute__((ext_vector_type(8)));
typedef float f32x4  __attribute__((ext_vector_type(4)));
typedef unsigned short u16x8 __attribute__((ext_vector_type(8)));

__device__ __forceinline__ unsigned short f2bf(float f) {
    unsigned u = __float_as_uint(f);
    unsigned r = (u + 0x7FFFu + ((u >> 16) & 1u)) >> 16;
    return (unsigned short)r;
}
__device__ __forceinline__ float b2f(unsigned short s) {
    return __uint_as_float(((unsigned)s) << 16);
}
__device__ __forceinline__ unsigned pk2bf(float lo, float hi) {
    __hip_bfloat162 h = __float22bfloat162_rn(float2{lo, hi});
    unsigned r;
    __builtin_memcpy(&r, &h, 4);
    return r;
}
__device__ __forceinline__ float fexp2(float x) {
#if __has_builtin(__builtin_amdgcn_exp2f)
    return __builtin_amdgcn_exp2f(x);
#else
    return exp2f(x);
#endif
}
__device__ __forceinline__ void gld16(void* lds, const void* g) {
    __builtin_amdgcn_global_load_lds(
        (const __attribute__((address_space(1))) unsigned int*)(g),
        (__attribute__((address_space(3))) unsigned int*)(lds),
        16, 0, 0);
}

// swizzled element offset for row-major [*][64] bf16 tiles (128B rows, 8 chunks of 16B)
#define SWZ(row, chunk) (((row) * 64) + (((chunk) ^ ((row) & 7)) << 3))

// ---------------- LayerNorm: fp32 in, bf16 out ----------------
__global__ __launch_bounds__(256) void ln_kernel(const float* __restrict__ x,
                                                 const float* __restrict__ gw,
                                                 const float* __restrict__ bw,
                                                 unsigned short* __restrict__ y)
{
    int row = blockIdx.x;
    int t = threadIdx.x;
    const float* xr = x + (size_t)row * HDIM;
    float4 v = *(const float4*)(xr + t * 4);
    float s1 = v.x + v.y + v.z + v.w;
    float s2 = v.x * v.x + v.y * v.y + v.z * v.z + v.w * v.w;
#pragma unroll
    for (int m = 1; m < 64; m <<= 1) {
        s1 += __shfl_xor(s1, m);
        s2 += __shfl_xor(s2, m);
    }
    __shared__ float red[8];
    int wid = t >> 6;
    if ((t & 63) == 0) { red[wid * 2] = s1; red[wid * 2 + 1] = s2; }
    __syncthreads();
    if (t == 0) {
        float a = red[0] + red[2] + red[4] + red[6];
        float b = red[1] + red[3] + red[5] + red[7];
        red[0] = a; red[1] = b;
    }
    __syncthreads();
    float mu  = red[0] * (1.0f / HDIM);
    float var = red[1] * (1.0f / HDIM) - mu * mu;
    float rs  = rsqrtf(var + 1e-5f);
    float4 g4 = *(const float4*)(gw + t * 4);
    float4 b4 = *(const float4*)(bw + t * 4);
    ushort4 o;
    o.x = f2bf((v.x - mu) * rs * g4.x + b4.x);
    o.y = f2bf((v.y - mu) * rs * g4.y + b4.y);
    o.z = f2bf((v.z - mu) * rs * g4.z + b4.z);
    o.w = f2bf((v.w - mu) * rs * g4.w + b4.w);
    *(ushort4*)(y + (size_t)row * HDIM + t * 4) = o;
}

// ------------- weight fp32 [K][N] -> bf16 transposed [N][K] -------------
__global__ __launch_bounds__(256) void wconv_kernel(const float* __restrict__ W,
                                                    unsigned short* __restrict__ WT,
                                                    int K, int N)
{
    __shared__ float tile[32][33];
    int n0 = blockIdx.x * 32, k0 = blockIdx.y * 32;
    int t = threadIdx.x, c = t & 31, r = t >> 5;
#pragma unroll
    for (int i = 0; i < 4; ++i)
        tile[r + 8 * i][c] = W[(size_t)(k0 + r + 8 * i) * N + n0 + c];
    __syncthreads();
#pragma unroll
    for (int i = 0; i < 4; ++i)
        WT[(size_t)(n0 + r + 8 * i) * K + k0 + c] = f2bf(tile[c][r + 8 * i]);
}

// ------------- MFMA GEMM 128x128 (round-1 verified): for N=1024 shapes -------------
// BK=64, double-buffered LDS (2x32KB), prefetch-before-compute, one barrier/K-tile.
template <int EPI>
__global__ __launch_bounds__(256, 2) void mgemm(const unsigned short* __restrict__ A,
                                                const unsigned short* __restrict__ BT,
                                                const float* __restrict__ bias,
                                                const float* __restrict__ resid,
                                                float* __restrict__ Cf,
                                                unsigned short* __restrict__ Cb,
                                                int M, int N, int K)
{
    __shared__ char smem[65536];   // [2 bufs][A 16KB | B 16KB]
    int t = threadIdx.x;
    int bn = blockIdx.x * 128, bm = blockIdx.y * 128;
    int l = t & 63, w = t >> 6;
    int wm = w >> 1, wn = w & 1;
    int lrow = l & 15, kq = l >> 4;

    f32x4 acc[4][4];
#pragma unroll
    for (int i = 0; i < 4; ++i)
#pragma unroll
        for (int j = 0; j < 4; ++j) acc[i][j] = {0.f, 0.f, 0.f, 0.f};

    const unsigned short* Ap[4];
    const unsigned short* Bp[4];
    int ld[4];
#pragma unroll
    for (int i = 0; i < 4; ++i) {
        int cid = i * 256 + t;
        int row = cid >> 3, c = cid & 7;
        int gc = (c ^ (row & 7)) << 3;
        Ap[i] = A + (size_t)(bm + row) * K + gc;
        Bp[i] = BT + (size_t)(bn + row) * K + gc;
        ld[i] = cid << 4;
    }

    int nt = K >> 6;
#pragma unroll
    for (int i = 0; i < 4; ++i) {
        gld16(smem + ld[i], Ap[i]);
        gld16(smem + 16384 + ld[i], Bp[i]);
    }
    __syncthreads();

    for (int tk = 0; tk < nt; ++tk) {
        int cur = (tk & 1) << 15;
        if (tk + 1 < nt) {
            int k0 = (tk + 1) << 6;
            int nxt = 32768 - cur;
#pragma unroll
            for (int i = 0; i < 4; ++i) {
                gld16(smem + nxt + ld[i], Ap[i] + k0);
                gld16(smem + nxt + 16384 + ld[i], Bp[i] + k0);
            }
        }
        const unsigned short* sA = (const unsigned short*)(smem + cur);
        const unsigned short* sB = (const unsigned short*)(smem + cur + 16384);
#pragma unroll
        for (int kk = 0; kk < 2; ++kk) {
            bf16x8 af[4], bv[4];
#pragma unroll
            for (int mi = 0; mi < 4; ++mi)
                af[mi] = *(const bf16x8*)(sA + SWZ(wm * 64 + mi * 16 + lrow, kk * 4 + kq));
#pragma unroll
            for (int ni = 0; ni < 4; ++ni)
                bv[ni] = *(const bf16x8*)(sB + SWZ(wn * 64 + ni * 16 + lrow, kk * 4 + kq));
#pragma unroll
            for (int mi = 0; mi < 4; ++mi)
#pragma unroll
                for (int ni = 0; ni < 4; ++ni)
                    acc[mi][ni] = __builtin_amdgcn_mfma_f32_16x16x32_bf16(af[mi], bv[ni], acc[mi][ni], 0, 0, 0);
        }
        __syncthreads();
    }

    int crow = (l >> 4) * 4;
    int ccol = l & 15;
#pragma unroll
    for (int mi = 0; mi < 4; ++mi) {
#pragma unroll
        for (int ni = 0; ni < 4; ++ni) {
            int gcol = bn + wn * 64 + ni * 16 + ccol;
            float bv = bias[gcol];
#pragma unroll
            for (int r = 0; r < 4; ++r) {
                int grow = bm + wm * 64 + mi * 16 + crow + r;
                size_t off = (size_t)grow * N + gcol;
                float v = acc[mi][ni][r] + bv;
                if (EPI == 1) {
                    Cf[off] = v + resid[off];
                } else if (EPI == 2) {
                    v = 0.5f * v * (1.0f + erff(v * 0.70710678118654752f));
                    Cb[off] = f2bf(v);
                } else {
                    Cb[off] = f2bf(v);
                }
            }
        }
    }
}

// ------------- MFMA GEMM 256x256, 8-PHASE counted-vmcnt schedule (T3+T4+T2+T5) -------
// BK=64 split into two K-halves of 32.  8 waves (2M x 4N), per-wave C = 128x64.
// LDS per buffer (64KB): A_kh0 16K | A_kh1 16K | B_kh0 16K | B_kh1 16K; 2 buffers.
// Half-tile h of K-tile t: h0=A kh0, h1=B kh0, h2=A kh1, h3=B kh1 (16KB each,
// 2 gld16/thread).  4 phases per K-tile; phase p: {8x ds_read (kk=p>>1,
// mi-group p&1) -> issue stage of H(t+1,p) into other buffer -> s_barrier ->
// lgkmcnt(0)+sched_barrier -> setprio(1) 16 MFMA setprio(0) -> [vmcnt(4) at
// p==1,3] -> s_barrier}.
// vmcnt(4) proof: end of phase 1, outstanding = {H(t,2),H(t,3),H(t+1,0),
// H(t+1,1)} = 8 loads; drain oldest 4 = H(t,2),H(t,3) = exactly what phases
// 2,3 read.  End of phase 3: outstanding = H(t+1,0..3); drain to H(t+1,0),
// H(t+1,1) = what next tile's phases 0,1 read.  4 loads always in flight
// across barriers (T4: never 0 in main loop).  WAR-safe: one full barrier
// between a buffer's last ds_read and its overwrite issue.
// K-half blocks are 256 rows x 32 k (64B rows, 4 chunks); swizzle chunk^(row&3)
// via pre-swizzled global source + swizzled ds_read (rule 21) -> uniform banks.
template <int EPI>
__global__ __launch_bounds__(512, 2) void mgemm8(const unsigned short* __restrict__ A,
                                                 const unsigned short* __restrict__ BT,
                                                 const float* __restrict__ bias,
                                                 unsigned short* __restrict__ Cb,
                                                 int M, int N, int K)
{
    __shared__ char smem[131072];
    int t = threadIdx.x;
    int bn = blockIdx.x * 256, bm = blockIdx.y * 256;
    int l = t & 63, w = t >> 6;
    int wm = w >> 2, wn = w & 3;     // 2M x 4N wave grid; per-wave 128x64
    int lr = l & 15, kq = l >> 4;

    f32x4 acc[8][4];
#pragma unroll
    for (int i = 0; i < 8; ++i)
#pragma unroll
        for (int j = 0; j < 4; ++j) acc[i][j] = {0.f, 0.f, 0.f, 0.f};

    // staging addresses: half-tile = 1024 chunks(16B); thread t stages chunks
    // t and t+512.  chunk cid: row=cid>>2, slot=cid&3; global k-chunk = slot^(row&3).
    int r0 = t >> 2, s0 = t & 3;
    int r1 = (t + 512) >> 2, s1 = (t + 512) & 3;
    const unsigned short* A0 = A + (size_t)(bm + r0) * K + ((s0 ^ (r0 & 3)) << 3);
    const unsigned short* A1 = A + (size_t)(bm + r1) * K + ((s1 ^ (r1 & 3)) << 3);
    const unsigned short* B0 = BT + (size_t)(bn + r0) * K + ((s0 ^ (r0 & 3)) << 3);
    const unsigned short* B1 = BT + (size_t)(bn + r1) * K + ((s1 ^ (r1 & 3)) << 3);
    int d0 = t << 4, d1 = (t + 512) << 4;

    // stage half-tile h of K-tile tk into buffer buf
#define STAGE8(buf, h, tk)                                                        \
    {                                                                             \
        size_t ko = (size_t)(tk) * 64 + (((h) >= 2) ? 32 : 0);                    \
        int bo = (buf) * 65536 + (((h) & 1) ? 32768 : 0) + (((h) >= 2) ? 16384 : 0); \
        const unsigned short* p0_ = ((h) & 1) ? B0 : A0;                          \
        const unsigned short* p1_ = ((h) & 1) ? B1 : A1;                          \
        gld16(smem + bo + d0, p0_ + ko);                                          \
        gld16(smem + bo + d1, p1_ + ko);                                          \
    }

    int nt = K >> 6;
    // prologue: stage K-tile 0 fully (4 half-tiles = 8 loads), wait first 2 halves
    STAGE8(0, 0, 0) STAGE8(0, 1, 0) STAGE8(0, 2, 0) STAGE8(0, 3, 0)
    asm volatile("s_waitcnt vmcnt(4)" ::: "memory");
    __builtin_amdgcn_s_barrier();

    for (int tk = 0; tk < nt; ++tk) {
        int cb = tk & 1, nb = cb ^ 1;
        bool pre = (tk + 1 < nt);
#pragma unroll
        for (int p = 0; p < 4; ++p) {
            const int kk = p >> 1;
            const unsigned short* Ablk = (const unsigned short*)(smem + cb * 65536 + kk * 16384);
            const unsigned short* Bblk = (const unsigned short*)(smem + cb * 65536 + 32768 + kk * 16384);
            bf16x8 af[4], bv[4];
#pragma unroll
            for (int m = 0; m < 4; ++m) {
                int row = wm * 128 + (p & 1) * 64 + m * 16 + lr;
                af[m] = *(const bf16x8*)(Ablk + row * 32 + ((kq ^ (row & 3)) << 3));
            }
#pragma unroll
            for (int n = 0; n < 4; ++n) {
                int row = wn * 64 + n * 16 + lr;
                bv[n] = *(const bf16x8*)(Bblk + row * 32 + ((kq ^ (row & 3)) << 3));
            }
            if (pre) STAGE8(nb, p, tk + 1)
            __builtin_amdgcn_s_barrier();
            asm volatile("s_waitcnt lgkmcnt(0)" ::: "memory");
            __builtin_amdgcn_sched_barrier(0);
            __builtin_amdgcn_s_setprio(1);
#pragma unroll
            for (int m = 0; m < 4; ++m)
#pragma unroll
                for (int n = 0; n < 4; ++n)
                    acc[(p & 1) * 4 + m][n] =
                        __builtin_amdgcn_mfma_f32_16x16x32_bf16(af[m], bv[n], acc[(p & 1) * 4 + m][n], 0, 0, 0);
            __builtin_amdgcn_s_setprio(0);
            if (p == 1 || p == 3) {
                if (pre) asm volatile("s_waitcnt vmcnt(4)" ::: "memory");
                else     asm volatile("s_waitcnt vmcnt(0)" ::: "memory");
            }
            __builtin_amdgcn_s_barrier();
        }
    }
#undef STAGE8

    int crow = (l >> 4) * 4;
    int ccol = l & 15;
#pragma unroll
    for (int mi = 0; mi < 8; ++mi) {
#pragma unroll
        for (int ni = 0; ni < 4; ++ni) {
            int gcol = bn + wn * 64 + ni * 16 + ccol;
            float bv = bias[gcol];
#pragma unroll
            for (int r = 0; r < 4; ++r) {
                int grow = bm + wm * 128 + mi * 16 + crow + r;
                size_t off = (size_t)grow * N + gcol;
                float v = acc[mi][ni][r] + bv;
                if (EPI == 2) {
                    v = 0.5f * v * (1.0f + erff(v * 0.70710678118654752f));
                    Cb[off] = f2bf(v);
                } else {
                    Cb[off] = f2bf(v);
                }
            }
        }
    }
}

// ---------------- MFMA flash attention (swapped QK^T, lane-local softmax) ----------------
// block = (q-tile of 64, head, batch); 4 waves, wave w owns q rows [16w,16w+16)
__global__ __launch_bounds__(256) void mattn(const unsigned short* __restrict__ qkv,
                                             unsigned short* __restrict__ out)
{
    __shared__ unsigned short Qs[64 * 64];     // [q][d] swizzled
    __shared__ unsigned short Ks[64 * 64];     // [k][d] swizzled
    __shared__ unsigned short Vt[64 * 64];     // [d][k] swizzled (transposed V)
    __shared__ unsigned short Ps[4 * 16 * 64]; // per-wave [q16][k64] swizzled
    int t = threadIdx.x;
    int w = t >> 6, l = t & 63;
    int lr = l & 15, lh = l >> 4;
    int q0 = blockIdx.x * 64;
    int hh = blockIdx.y, b = blockIdx.z;
    const unsigned short* Qg = qkv + (size_t)b * SEQ * 3072 + hh * 64;
    const unsigned short* Kg = Qg + 1024;
    const unsigned short* Vg = Qg + 2048;

    // ---- stage Q (pre-swizzled global source) ----
#pragma unroll
    for (int i = 0; i < 2; ++i) {
        int chunkid = (w * 2 + i) * 64 + l;
        int row = chunkid >> 3, c = chunkid & 7;
        gld16(((char*)Qs) + chunkid * 16,
              Qg + (size_t)(q0 + row) * 3072 + ((c ^ (row & 7)) << 3));
    }
    __syncthreads();
    bf16x8 qa[2];
#pragma unroll
    for (int ks = 0; ks < 2; ++ks)
        qa[ks] = *(const bf16x8*)(Qs + SWZ(w * 16 + lr, ks * 4 + lh));

    f32x4 o[4];
#pragma unroll
    for (int i = 0; i < 4; ++i) o[i] = {0.f, 0.f, 0.f, 0.f};
    float mr = -3.0e38f, lsum = 0.f;   // per-lane: q-row = w*16 + lr
    unsigned short* Pw = Ps + w * (16 * 64);
    const float C = 0.18033688011112042f;  // 0.125 * log2(e)

    // hoisted staging pointers (advance by 64 rows per tile)
    int ck0 = (w * 2) * 64 + l, ck1 = (w * 2 + 1) * 64 + l;
    int kr0 = ck0 >> 3, kc0 = ck0 & 7;
    int kr1 = ck1 >> 3, kc1 = ck1 & 7;
    const unsigned short* Kp0 = Kg + (size_t)kr0 * 3072 + ((kc0 ^ (kr0 & 7)) << 3);
    const unsigned short* Kp1 = Kg + (size_t)kr1 * 3072 + ((kc1 ^ (kr1 & 7)) << 3);
    char* Kd0 = (char*)Ks + ck0 * 16;
    char* Kd1 = (char*)Ks + ck1 * 16;
    int vk = (t & 31) * 2;
    int vd0 = ((t >> 5) & 7) * 8;
    const unsigned short* Vp0 = Vg + (size_t)vk * 3072 + vd0;
    const unsigned short* Vp1 = Vp0 + 3072;

    for (int kv = 0; kv < SEQ; kv += 64) {
        __syncthreads();  // all waves done reading prev K/V
        gld16(Kd0, Kp0);
        gld16(Kd1, Kp1);
        u16x8 v0 = *(const u16x8*)Vp0;
        u16x8 v1 = *(const u16x8*)Vp1;
        Kp0 += 64 * 3072; Kp1 += 64 * 3072;
        Vp0 += 64 * 3072; Vp1 += 64 * 3072;
#pragma unroll
        for (int j = 0; j < 8; ++j) {
            int d = vd0 + j;
            unsigned pack = (unsigned)(unsigned short)v0[j] | ((unsigned)(unsigned short)v1[j] << 16);
            *(unsigned*)(Vt + SWZ(d, vk >> 3) + (vk & 7)) = pack;
        }
        __syncthreads();  // K/V staged

        // swapped QK^T: S^T = K·Q^T -> lane holds q=lr, k=ni*16+lh*4+r (raw scores)
        f32x4 s[4];
#pragma unroll
        for (int ni = 0; ni < 4; ++ni) s[ni] = {0.f, 0.f, 0.f, 0.f};
#pragma unroll
        for (int ks = 0; ks < 2; ++ks) {
#pragma unroll
            for (int ni = 0; ni < 4; ++ni) {
                bf16x8 kb = *(const bf16x8*)(Ks + SWZ(ni * 16 + lr, ks * 4 + lh));
                s[ni] = __builtin_amdgcn_mfma_f32_16x16x32_bf16(kb, qa[ks], s[ni], 0, 0, 0);
            }
        }
        // row max: 15 in-reg + 2 shfl (lanes sharing lr)
        float mx = s[0][0];
#pragma unroll
        for (int ni = 0; ni < 4; ++ni)
#pragma unroll
            for (int r = 0; r < 4; ++r) mx = fmaxf(mx, s[ni][r]);
        mx = fmaxf(mx, __shfl_xor(mx, 16));
        mx = fmaxf(mx, __shfl_xor(mx, 32));
        // defer-max: only rescale when growth beyond e^8 bound (always on tile 0)
        if (__any(mx > mr + 64.0f)) {
            float mn = fmaxf(mr, mx);
            float corr = fexp2((mr - mn) * C);
            mr = mn;
            lsum *= corr;
            float cr[4];
#pragma unroll
            for (int r = 0; r < 4; ++r) cr[r] = __shfl(corr, lh * 4 + r, 16);
#pragma unroll
            for (int nd = 0; nd < 4; ++nd) {
                o[nd][0] *= cr[0]; o[nd][1] *= cr[1];
                o[nd][2] *= cr[2]; o[nd][3] *= cr[3];
            }
        }
        float mc = mr * C;
        float rsum = 0.f;
#pragma unroll
        for (int ni = 0; ni < 4; ++ni)
#pragma unroll
            for (int r = 0; r < 4; ++r) {
                float p = fexp2(fmaf(s[ni][r], C, -mc));
                s[ni][r] = p;
                rsum += p;
            }
        rsum += __shfl_xor(rsum, 16);
        rsum += __shfl_xor(rsum, 32);
        lsum += rsum;
        // P write: packed pairs (adjacent k = r, r+1)
#pragma unroll
        for (int ni = 0; ni < 4; ++ni)
#pragma unroll
            for (int rp = 0; rp < 2; ++rp) {
                int k = ni * 16 + lh * 4 + rp * 2;
                *(unsigned*)(Pw + SWZ(lr, k >> 3) + (k & 7)) =
                    pk2bf(s[ni][rp * 2], s[ni][rp * 2 + 1]);
            }
        // PV: O[q16][d64] += P[q16][k64] @ V[k64][d64]
#pragma unroll
        for (int ks = 0; ks < 2; ++ks) {
            bf16x8 pa = *(const bf16x8*)(Pw + SWZ(lr, ks * 4 + lh));
#pragma unroll
            for (int nd = 0; nd < 4; ++nd) {
                bf16x8 vb = *(const bf16x8*)(Vt + SWZ(nd * 16 + lr, ks * 4 + lh));
                o[nd] = __builtin_amdgcn_mfma_f32_16x16x32_bf16(pa, vb, o[nd], 0, 0, 0);
            }
        }
    }
    // epilogue: redistribute 1/lsum to PV row owners
    float inv = 1.0f / lsum;
    float ir[4];
#pragma unroll
    for (int r = 0; r < 4; ++r) ir[r] = __shfl(inv, lh * 4 + r, 16);
#pragma unroll
    for (int r = 0; r < 4; ++r) {
        int q = q0 + w * 16 + lh * 4 + r;
#pragma unroll
        for (int nd = 0; nd < 4; ++nd) {
            int d = nd * 16 + lr;
            out[(size_t)((size_t)b * SEQ + q) * HDIM + hh * 64 + d] = f2bf(o[nd][r] * ir[r]);
        }
    }
}

extern "C" void kernel_launch(void* const* d_in, const int* in_sizes, int n_in,
                              void* d_out, int out_size, void* d_ws, size_t ws_size,
                              hipStream_t stream)
{
    const float* x     = (const float*)d_in[0];
    const float* ln1_g = (const float*)d_in[1];
    const float* ln1_b = (const float*)d_in[2];
    const float* W_qkv = (const float*)d_in[3];
    const float* b_qkv = (const float*)d_in[4];
    const float* W_out = (const float*)d_in[5];
    const float* b_out = (const float*)d_in[6];
    const float* ln2_g = (const float*)d_in[7];
    const float* ln2_b = (const float*)d_in[8];
    const float* W1    = (const float*)d_in[9];
    const float* b1    = (const float*)d_in[10];
    const float* W2    = (const float*)d_in[11];
    const float* b2    = (const float*)d_in[12];
    float* out = (float*)d_out;
    char* ws8  = (char*)d_ws;

    const int M = BATCH * SEQ;  // 4096
    const size_t MB = 1048576;

    unsigned short* hbuf = (unsigned short*)(ws8);
    unsigned short* qkvb = (unsigned short*)(ws8 + 8 * MB);
    unsigned short* attb = (unsigned short*)(ws8 + 32 * MB);
    unsigned short* ffn1 = (unsigned short*)(ws8 + 8 * MB);
    unsigned short* WqT  = (unsigned short*)(ws8 + 40 * MB);
    unsigned short* WoT  = (unsigned short*)(ws8 + 46 * MB);
    unsigned short* W1T  = (unsigned short*)(ws8 + 48 * MB);
    unsigned short* W2T  = (unsigned short*)(ws8 + 56 * MB);

    wconv_kernel<<<dim3(3 * HDIM / 32, HDIM / 32), 256, 0, stream>>>(W_qkv, WqT, HDIM, 3 * HDIM);
    wconv_kernel<<<dim3(HDIM / 32, HDIM / 32), 256, 0, stream>>>(W_out, WoT, HDIM, HDIM);
    wconv_kernel<<<dim3(4 * HDIM / 32, HDIM / 32), 256, 0, stream>>>(W1, W1T, HDIM, 4 * HDIM);
    wconv_kernel<<<dim3(HDIM / 32, 4 * HDIM / 32), 256, 0, stream>>>(W2, W2T, 4 * HDIM, HDIM);

    ln_kernel<<<M, 256, 0, stream>>>(x, ln1_g, ln1_b, hbuf);
    // QKV: 256x256 8-phase (grid 12x16 = 192 blocks)
    mgemm8<0><<<dim3(3 * HDIM / 256, M / 256), 512, 0, stream>>>(hbuf, WqT, b_qkv, qkvb, M, 3 * HDIM, HDIM);
    mattn<<<dim3(SEQ / 64, NHEAD, BATCH), 256, 0, stream>>>(qkvb, attb);
    // out-proj: 128x128 (grid 8x32 = 256 blocks, exact fill), fused residual
    mgemm<1><<<dim3(HDIM / 128, M / 128), 256, 0, stream>>>(attb, WoT, b_out, x, out, nullptr, M, HDIM, HDIM);
    ln_kernel<<<M, 256, 0, stream>>>(out, ln2_g, ln2_b, hbuf);
    // FFN1: 256x256 8-phase (grid 16x16 = 256 blocks, exact fill), fused gelu
    mgemm8<2><<<dim3(4 * HDIM / 256, M / 256), 512, 0, stream>>>(hbuf, W1T, b1, ffn1, M, 4 * HDIM, HDIM);
    // FFN2: 128x128, fused residual (in-place on out)
    mgemm<1><<<dim3(HDIM / 128, M / 128), 256, 0, stream>>>(ffn1, W2T, b2, out, out, nullptr, M, HDIM, 4 * HDIM);
}

// Round 5
// 255.139 us; speedup vs baseline: 1.1463x; 1.1463x over previous
//
#include <hip/hip_runtime.h>
#include <hip/hip_bf16.h>
#include <math.h>

#define HDIM 1024
#define SEQ  2048
#define BATCH 2
#define NHEAD 16
#define HEADD 64

typedef short bf16x8 __attribute__((ext_vector_type(8)));
typedef float f32x4  __attribute__((ext_vector_type(4)));
typedef unsigned short u16x8 __attribute__((ext_vector_type(8)));

__device__ __forceinline__ unsigned short f2bf(float f) {
    unsigned u = __float_as_uint(f);
    unsigned r = (u + 0x7FFFu + ((u >> 16) & 1u)) >> 16;
    return (unsigned short)r;
}
__device__ __forceinline__ float b2f(unsigned short s) {
    return __uint_as_float(((unsigned)s) << 16);
}
__device__ __forceinline__ unsigned pk2bf(float lo, float hi) {
    __hip_bfloat162 h = __float22bfloat162_rn(float2{lo, hi});
    unsigned r;
    __builtin_memcpy(&r, &h, 4);
    return r;
}
__device__ __forceinline__ float fexp2(float x) {
#if __has_builtin(__builtin_amdgcn_exp2f)
    return __builtin_amdgcn_exp2f(x);
#else
    return exp2f(x);
#endif
}
__device__ __forceinline__ void gld16(void* lds, const void* g) {
    __builtin_amdgcn_global_load_lds(
        (const __attribute__((address_space(1))) unsigned int*)(g),
        (__attribute__((address_space(3))) unsigned int*)(lds),
        16, 0, 0);
}

// swizzled element offset for row-major [*][64] bf16 tiles (128B rows, 8 chunks of 16B)
#define SWZ(row, chunk) (((row) * 64) + (((chunk) ^ ((row) & 7)) << 3))

// ---------------- LayerNorm: fp32 in, bf16 out ----------------
__global__ __launch_bounds__(256) void ln_kernel(const float* __restrict__ x,
                                                 const float* __restrict__ gw,
                                                 const float* __restrict__ bw,
                                                 unsigned short* __restrict__ y)
{
    int row = blockIdx.x;
    int t = threadIdx.x;
    const float* xr = x + (size_t)row * HDIM;
    float4 v = *(const float4*)(xr + t * 4);
    float s1 = v.x + v.y + v.z + v.w;
    float s2 = v.x * v.x + v.y * v.y + v.z * v.z + v.w * v.w;
#pragma unroll
    for (int m = 1; m < 64; m <<= 1) {
        s1 += __shfl_xor(s1, m);
        s2 += __shfl_xor(s2, m);
    }
    __shared__ float red[8];
    int wid = t >> 6;
    if ((t & 63) == 0) { red[wid * 2] = s1; red[wid * 2 + 1] = s2; }
    __syncthreads();
    if (t == 0) {
        float a = red[0] + red[2] + red[4] + red[6];
        float b = red[1] + red[3] + red[5] + red[7];
        red[0] = a; red[1] = b;
    }
    __syncthreads();
    float mu  = red[0] * (1.0f / HDIM);
    float var = red[1] * (1.0f / HDIM) - mu * mu;
    float rs  = rsqrtf(var + 1e-5f);
    float4 g4 = *(const float4*)(gw + t * 4);
    float4 b4 = *(const float4*)(bw + t * 4);
    ushort4 o;
    o.x = f2bf((v.x - mu) * rs * g4.x + b4.x);
    o.y = f2bf((v.y - mu) * rs * g4.y + b4.y);
    o.z = f2bf((v.z - mu) * rs * g4.z + b4.z);
    o.w = f2bf((v.w - mu) * rs * g4.w + b4.w);
    *(ushort4*)(y + (size_t)row * HDIM + t * 4) = o;
}

// ------------- weight fp32 [K][N] -> bf16 transposed [N][K] -------------
__global__ __launch_bounds__(256) void wconv_kernel(const float* __restrict__ W,
                                                    unsigned short* __restrict__ WT,
                                                    int K, int N)
{
    __shared__ float tile[32][33];
    int n0 = blockIdx.x * 32, k0 = blockIdx.y * 32;
    int t = threadIdx.x, c = t & 31, r = t >> 5;
#pragma unroll
    for (int i = 0; i < 4; ++i)
        tile[r + 8 * i][c] = W[(size_t)(k0 + r + 8 * i) * N + n0 + c];
    __syncthreads();
#pragma unroll
    for (int i = 0; i < 4; ++i)
        WT[(size_t)(n0 + r + 8 * i) * K + k0 + c] = f2bf(tile[c][r + 8 * i]);
}

// ------------- MFMA GEMM: C[M,N] = A[M,K] @ BT[N,K]^T + bias (+EPI) -------------
// 128x128 tile, BK=64, double-buffered LDS (2x32KB), prefetch-before-compute,
// one barrier per K-tile (round-1 verified best: FFN1-class 88.6us, 0 conflicts).
template <int EPI>
__global__ __launch_bounds__(256, 2) void mgemm(const unsigned short* __restrict__ A,
                                                const unsigned short* __restrict__ BT,
                                                const float* __restrict__ bias,
                                                const float* __restrict__ resid,
                                                float* __restrict__ Cf,
                                                unsigned short* __restrict__ Cb,
                                                int M, int N, int K)
{
    __shared__ char smem[65536];   // [2 bufs][A 16KB | B 16KB]
    int t = threadIdx.x;
    int bn = blockIdx.x * 128, bm = blockIdx.y * 128;
    int l = t & 63, w = t >> 6;
    int wm = w >> 1, wn = w & 1;
    int lrow = l & 15, kq = l >> 4;

    f32x4 acc[4][4];
#pragma unroll
    for (int i = 0; i < 4; ++i)
#pragma unroll
        for (int j = 0; j < 4; ++j) acc[i][j] = {0.f, 0.f, 0.f, 0.f};

    const unsigned short* Ap[4];
    const unsigned short* Bp[4];
    int ld[4];
#pragma unroll
    for (int i = 0; i < 4; ++i) {
        int cid = i * 256 + t;
        int row = cid >> 3, c = cid & 7;
        int gc = (c ^ (row & 7)) << 3;
        Ap[i] = A + (size_t)(bm + row) * K + gc;
        Bp[i] = BT + (size_t)(bn + row) * K + gc;
        ld[i] = cid << 4;
    }

    int nt = K >> 6;
#pragma unroll
    for (int i = 0; i < 4; ++i) {
        gld16(smem + ld[i], Ap[i]);
        gld16(smem + 16384 + ld[i], Bp[i]);
    }
    __syncthreads();

    for (int tk = 0; tk < nt; ++tk) {
        int cur = (tk & 1) << 15;
        if (tk + 1 < nt) {
            int k0 = (tk + 1) << 6;
            int nxt = 32768 - cur;
#pragma unroll
            for (int i = 0; i < 4; ++i) {
                gld16(smem + nxt + ld[i], Ap[i] + k0);
                gld16(smem + nxt + 16384 + ld[i], Bp[i] + k0);
            }
        }
        const unsigned short* sA = (const unsigned short*)(smem + cur);
        const unsigned short* sB = (const unsigned short*)(smem + cur + 16384);
#pragma unroll
        for (int kk = 0; kk < 2; ++kk) {
            bf16x8 af[4], bv[4];
#pragma unroll
            for (int mi = 0; mi < 4; ++mi)
                af[mi] = *(const bf16x8*)(sA + SWZ(wm * 64 + mi * 16 + lrow, kk * 4 + kq));
#pragma unroll
            for (int ni = 0; ni < 4; ++ni)
                bv[ni] = *(const bf16x8*)(sB + SWZ(wn * 64 + ni * 16 + lrow, kk * 4 + kq));
#pragma unroll
            for (int mi = 0; mi < 4; ++mi)
#pragma unroll
                for (int ni = 0; ni < 4; ++ni)
                    acc[mi][ni] = __builtin_amdgcn_mfma_f32_16x16x32_bf16(af[mi], bv[ni], acc[mi][ni], 0, 0, 0);
        }
        __syncthreads();
    }

    int crow = (l >> 4) * 4;
    int ccol = l & 15;
#pragma unroll
    for (int mi = 0; mi < 4; ++mi) {
#pragma unroll
        for (int ni = 0; ni < 4; ++ni) {
            int gcol = bn + wn * 64 + ni * 16 + ccol;
            float bv = bias[gcol];
#pragma unroll
            for (int r = 0; r < 4; ++r) {
                int grow = bm + wm * 64 + mi * 16 + crow + r;
                size_t off = (size_t)grow * N + gcol;
                float v = acc[mi][ni][r] + bv;
                if (EPI == 1) {
                    Cf[off] = v + resid[off];
                } else if (EPI == 2) {
                    v = 0.5f * v * (1.0f + erff(v * 0.70710678118654752f));
                    Cb[off] = f2bf(v);
                } else {
                    Cb[off] = f2bf(v);
                }
            }
        }
    }
}

// ---------------- MFMA flash attention v2: double-buffered K/V, reg-staged
// prefetch across RAW s_barrier (T14).  Per KV-tile the old kernel exposed the
// full K/V fetch latency between two __syncthreads (whose vmcnt(0) drain also
// killed any prefetch).  Now: K and V for tile t+2 are loaded into REGISTERS
// during tile t's compute (regs need no barrier ordering), written to the
// alternate LDS buffer after compute, published with lgkmcnt(0)+s_barrier
// (raw barrier: no vmcnt drain, prefetch loads stay in flight).  The ds_write's
// implicit vmcnt wait lands one full compute phase after issue -> hidden.
// LDS 49KB -> 3 blocks/CU.  WAR-safe: buffer nb was last READ in tile t-1;
// those reads completed before the barrier separating t-1 and t (data consumed
// by MFMAs), and writes to nb happen after tile t's compute, one barrier later.
__global__ __launch_bounds__(256) void mattn(const unsigned short* __restrict__ qkv,
                                             unsigned short* __restrict__ out)
{
    __shared__ unsigned short Qs[64 * 64];        // [q][d] swizzled
    __shared__ unsigned short Ks[2][64 * 64];     // [k][d] swizzled, double-buffered
    __shared__ unsigned short Vt[2][64 * 64];     // [d][k] swizzled (transposed V)
    __shared__ unsigned short Ps[4 * 16 * 64];    // per-wave [q16][k64] swizzled
    int t = threadIdx.x;
    int w = t >> 6, l = t & 63;
    int lr = l & 15, lh = l >> 4;
    int q0 = blockIdx.x * 64;
    int hh = blockIdx.y, b = blockIdx.z;
    const unsigned short* Qg = qkv + (size_t)b * SEQ * 3072 + hh * 64;
    const unsigned short* Kg = Qg + 1024;
    const unsigned short* Vg = Qg + 2048;

    // ---- stage Q via gld16 (pre-swizzled global source) ----
#pragma unroll
    for (int i = 0; i < 2; ++i) {
        int chunkid = (w * 2 + i) * 64 + l;
        int row = chunkid >> 3, c = chunkid & 7;
        gld16(((char*)Qs) + chunkid * 16,
              Qg + (size_t)(q0 + row) * 3072 + ((c ^ (row & 7)) << 3));
    }

    // ---- K reg-staging geometry: 512 chunks (64 rows x 8), 2 per thread ----
    int kr0 = t >> 3, kc0 = t & 7;            // chunk t
    int kr1 = (t + 256) >> 3;                 // chunk t+256 (same kc)
    const unsigned short* Kp0 = Kg + (size_t)kr0 * 3072 + kc0 * 8;
    const unsigned short* Kp1 = Kg + (size_t)kr1 * 3072 + kc0 * 8;
    int kd0 = SWZ(kr0, kc0);                  // swizzled LDS element offsets
    int kd1 = SWZ(kr1, kc0);
    // ---- V geometry (2 columns of 8 d-elems per thread) ----
    int vk = (t & 31) * 2;
    int vd0 = ((t >> 5) & 7) * 8;
    const unsigned short* Vp0 = Vg + (size_t)vk * 3072 + vd0;
    const unsigned short* Vp1 = Vp0 + 3072;

    // prologue: load K/V tile 0 to regs
    u16x8 k0 = *(const u16x8*)Kp0;
    u16x8 k1 = *(const u16x8*)Kp1;
    u16x8 v0 = *(const u16x8*)Vp0;
    u16x8 v1 = *(const u16x8*)Vp1;
    Kp0 += 64 * 3072; Kp1 += 64 * 3072; Vp0 += 64 * 3072; Vp1 += 64 * 3072;

    __syncthreads();   // Qs ready (full drain; prologue only)
    bf16x8 qa[2];
#pragma unroll
    for (int ks = 0; ks < 2; ++ks)
        qa[ks] = *(const bf16x8*)(Qs + SWZ(w * 16 + lr, ks * 4 + lh));

    // write tile 0 into buffer 0
    *(u16x8*)(Ks[0] + kd0) = k0;
    *(u16x8*)(Ks[0] + kd1) = k1;
#pragma unroll
    for (int j = 0; j < 8; ++j) {
        int d = vd0 + j;
        unsigned pack = (unsigned)(unsigned short)v0[j] | ((unsigned)(unsigned short)v1[j] << 16);
        *(unsigned*)(Vt[0] + SWZ(d, vk >> 3) + (vk & 7)) = pack;
    }
    // prefetch tile 1 to regs (stays in flight across the raw barrier)
    k0 = *(const u16x8*)Kp0; k1 = *(const u16x8*)Kp1;
    v0 = *(const u16x8*)Vp0; v1 = *(const u16x8*)Vp1;
    Kp0 += 64 * 3072; Kp1 += 64 * 3072; Vp0 += 64 * 3072; Vp1 += 64 * 3072;
    asm volatile("s_waitcnt lgkmcnt(0)" ::: "memory");   // publish buf0 writes
    __builtin_amdgcn_s_barrier();

    f32x4 o[4];
#pragma unroll
    for (int i = 0; i < 4; ++i) o[i] = {0.f, 0.f, 0.f, 0.f};
    float mr = -3.0e38f, lsum = 0.f;   // per-lane: q-row = w*16 + lr
    unsigned short* Pw = Ps + w * (16 * 64);
    const float C = 0.18033688011112042f;  // 0.125 * log2(e)

    const int nt = SEQ / 64;   // 32
    for (int tt = 0; tt < nt; ++tt) {
        const unsigned short* Kc = Ks[tt & 1];
        const unsigned short* Vc = Vt[tt & 1];

        // swapped QK^T: S^T = K·Q^T -> lane holds q=lr, k=ni*16+lh*4+r
        f32x4 s[4];
#pragma unroll
        for (int ni = 0; ni < 4; ++ni) s[ni] = {0.f, 0.f, 0.f, 0.f};
#pragma unroll
        for (int ks = 0; ks < 2; ++ks) {
#pragma unroll
            for (int ni = 0; ni < 4; ++ni) {
                bf16x8 kb = *(const bf16x8*)(Kc + SWZ(ni * 16 + lr, ks * 4 + lh));
                s[ni] = __builtin_amdgcn_mfma_f32_16x16x32_bf16(kb, qa[ks], s[ni], 0, 0, 0);
            }
        }
        // row max: 15 in-reg + 2 shfl (lanes sharing lr)
        float mx = s[0][0];
#pragma unroll
        for (int ni = 0; ni < 4; ++ni)
#pragma unroll
            for (int r = 0; r < 4; ++r) mx = fmaxf(mx, s[ni][r]);
        mx = fmaxf(mx, __shfl_xor(mx, 16));
        mx = fmaxf(mx, __shfl_xor(mx, 32));
        // defer-max: only rescale when growth beyond e^8 bound (always on tile 0)
        if (__any(mx > mr + 64.0f)) {
            float mn = fmaxf(mr, mx);
            float corr = fexp2((mr - mn) * C);
            mr = mn;
            lsum *= corr;
            float cr[4];
#pragma unroll
            for (int r = 0; r < 4; ++r) cr[r] = __shfl(corr, lh * 4 + r, 16);
#pragma unroll
            for (int nd = 0; nd < 4; ++nd) {
                o[nd][0] *= cr[0]; o[nd][1] *= cr[1];
                o[nd][2] *= cr[2]; o[nd][3] *= cr[3];
            }
        }
        float mc = mr * C;
        float rsum = 0.f;
#pragma unroll
        for (int ni = 0; ni < 4; ++ni)
#pragma unroll
            for (int r = 0; r < 4; ++r) {
                float p = fexp2(fmaf(s[ni][r], C, -mc));
                s[ni][r] = p;
                rsum += p;
            }
        rsum += __shfl_xor(rsum, 16);
        rsum += __shfl_xor(rsum, 32);
        lsum += rsum;
        // P write: packed pairs (adjacent k = r, r+1)
#pragma unroll
        for (int ni = 0; ni < 4; ++ni)
#pragma unroll
            for (int rp = 0; rp < 2; ++rp) {
                int k = ni * 16 + lh * 4 + rp * 2;
                *(unsigned*)(Pw + SWZ(lr, k >> 3) + (k & 7)) =
                    pk2bf(s[ni][rp * 2], s[ni][rp * 2 + 1]);
            }
        // PV: O[q16][d64] += P[q16][k64] @ V[k64][d64]
#pragma unroll
        for (int ks = 0; ks < 2; ++ks) {
            bf16x8 pa = *(const bf16x8*)(Pw + SWZ(lr, ks * 4 + lh));
#pragma unroll
            for (int nd = 0; nd < 4; ++nd) {
                bf16x8 vb = *(const bf16x8*)(Vc + SWZ(nd * 16 + lr, ks * 4 + lh));
                o[nd] = __builtin_amdgcn_mfma_f32_16x16x32_bf16(pa, vb, o[nd], 0, 0, 0);
            }
        }

        // ---- post-compute: write next tile's K/V (regs -> LDS), prefetch t+2 ----
        if (tt + 1 < nt) {
            int nb = (tt & 1) ^ 1;
            // implicit vmcnt wait here covers loads issued one full tile ago
            *(u16x8*)(Ks[nb] + kd0) = k0;
            *(u16x8*)(Ks[nb] + kd1) = k1;
#pragma unroll
            for (int j = 0; j < 8; ++j) {
                int d = vd0 + j;
                unsigned pack = (unsigned)(unsigned short)v0[j] | ((unsigned)(unsigned short)v1[j] << 16);
                *(unsigned*)(Vt[nb] + SWZ(d, vk >> 3) + (vk & 7)) = pack;
            }
            if (tt + 2 < nt) {
                k0 = *(const u16x8*)Kp0; k1 = *(const u16x8*)Kp1;
                v0 = *(const u16x8*)Vp0; v1 = *(const u16x8*)Vp1;
                Kp0 += 64 * 3072; Kp1 += 64 * 3072; Vp0 += 64 * 3072; Vp1 += 64 * 3072;
            }
            asm volatile("s_waitcnt lgkmcnt(0)" ::: "memory");  // publish nb writes
            __builtin_amdgcn_s_barrier();                        // raw: no vmcnt drain
        }
    }
    // epilogue: redistribute 1/lsum to PV row owners
    float inv = 1.0f / lsum;
    float ir[4];
#pragma unroll
    for (int r = 0; r < 4; ++r) ir[r] = __shfl(inv, lh * 4 + r, 16);
#pragma unroll
    for (int r = 0; r < 4; ++r) {
        int q = q0 + w * 16 + lh * 4 + r;
#pragma unroll
        for (int nd = 0; nd < 4; ++nd) {
            int d = nd * 16 + lr;
            out[(size_t)((size_t)b * SEQ + q) * HDIM + hh * 64 + d] = f2bf(o[nd][r] * ir[r]);
        }
    }
}

extern "C" void kernel_launch(void* const* d_in, const int* in_sizes, int n_in,
                              void* d_out, int out_size, void* d_ws, size_t ws_size,
                              hipStream_t stream)
{
    const float* x     = (const float*)d_in[0];
    const float* ln1_g = (const float*)d_in[1];
    const float* ln1_b = (const float*)d_in[2];
    const float* W_qkv = (const float*)d_in[3];
    const float* b_qkv = (const float*)d_in[4];
    const float* W_out = (const float*)d_in[5];
    const float* b_out = (const float*)d_in[6];
    const float* ln2_g = (const float*)d_in[7];
    const float* ln2_b = (const float*)d_in[8];
    const float* W1    = (const float*)d_in[9];
    const float* b1    = (const float*)d_in[10];
    const float* W2    = (const float*)d_in[11];
    const float* b2    = (const float*)d_in[12];
    float* out = (float*)d_out;
    char* ws8  = (char*)d_ws;

    const int M = BATCH * SEQ;  // 4096
    const size_t MB = 1048576;

    unsigned short* hbuf = (unsigned short*)(ws8);
    unsigned short* qkvb = (unsigned short*)(ws8 + 8 * MB);
    unsigned short* attb = (unsigned short*)(ws8 + 32 * MB);
    unsigned short* ffn1 = (unsigned short*)(ws8 + 8 * MB);
    unsigned short* WqT  = (unsigned short*)(ws8 + 40 * MB);
    unsigned short* WoT  = (unsigned short*)(ws8 + 46 * MB);
    unsigned short* W1T  = (unsigned short*)(ws8 + 48 * MB);
    unsigned short* W2T  = (unsigned short*)(ws8 + 56 * MB);

    wconv_kernel<<<dim3(3 * HDIM / 32, HDIM / 32), 256, 0, stream>>>(W_qkv, WqT, HDIM, 3 * HDIM);
    wconv_kernel<<<dim3(HDIM / 32, HDIM / 32), 256, 0, stream>>>(W_out, WoT, HDIM, HDIM);
    wconv_kernel<<<dim3(4 * HDIM / 32, HDIM / 32), 256, 0, stream>>>(W1, W1T, HDIM, 4 * HDIM);
    wconv_kernel<<<dim3(HDIM / 32, 4 * HDIM / 32), 256, 0, stream>>>(W2, W2T, 4 * HDIM, HDIM);

    ln_kernel<<<M, 256, 0, stream>>>(x, ln1_g, ln1_b, hbuf);
    mgemm<0><<<dim3(3 * HDIM / 128, M / 128), 256, 0, stream>>>(hbuf, WqT, b_qkv, nullptr, nullptr, qkvb, M, 3 * HDIM, HDIM);
    mattn<<<dim3(SEQ / 64, NHEAD, BATCH), 256, 0, stream>>>(qkvb, attb);
    mgemm<1><<<dim3(HDIM / 128, M / 128), 256, 0, stream>>>(attb, WoT, b_out, x, out, nullptr, M, HDIM, HDIM);
    ln_kernel<<<M, 256, 0, stream>>>(out, ln2_g, ln2_b, hbuf);
    mgemm<2><<<dim3(4 * HDIM / 128, M / 128), 256, 0, stream>>>(hbuf, W1T, b1, nullptr, nullptr, ffn1, M, 4 * HDIM, HDIM);
    mgemm<1><<<dim3(HDIM / 128, M / 128), 256, 0, stream>>>(ffn1, W2T, b2, out, out, nullptr, M, HDIM, 4 * HDIM);
}

// Round 6
// 232.290 us; speedup vs baseline: 1.2590x; 1.0984x over previous
//
#include <hip/hip_runtime.h>
#include <hip/hip_bf16.h>
#include <math.h>

#define HDIM 1024
#define SEQ  2048
#define BATCH 2
#define NHEAD 16
#define HEADD 64

typedef short bf16x8 __attribute__((ext_vector_type(8)));
typedef float f32x4  __attribute__((ext_vector_type(4)));
typedef unsigned short u16x8 __attribute__((ext_vector_type(8)));
typedef unsigned short u16x4 __attribute__((ext_vector_type(4)));

__device__ __forceinline__ unsigned short f2bf(float f) {
    unsigned u = __float_as_uint(f);
    unsigned r = (u + 0x7FFFu + ((u >> 16) & 1u)) >> 16;
    return (unsigned short)r;
}
__device__ __forceinline__ float b2f(unsigned short s) {
    return __uint_as_float(((unsigned)s) << 16);
}
__device__ __forceinline__ unsigned pk2bf(float lo, float hi) {
    __hip_bfloat162 h = __float22bfloat162_rn(float2{lo, hi});
    unsigned r;
    __builtin_memcpy(&r, &h, 4);
    return r;
}
__device__ __forceinline__ float fexp2(float x) {
#if __has_builtin(__builtin_amdgcn_exp2f)
    return __builtin_amdgcn_exp2f(x);
#else
    return exp2f(x);
#endif
}
__device__ __forceinline__ void gld16(void* lds, const void* g) {
    __builtin_amdgcn_global_load_lds(
        (const __attribute__((address_space(1))) unsigned int*)(g),
        (__attribute__((address_space(3))) unsigned int*)(lds),
        16, 0, 0);
}

// swizzled element offset for row-major [*][64] bf16 tiles (128B rows, 8 chunks of 16B)
#define SWZ(row, chunk) (((row) * 64) + (((chunk) ^ ((row) & 7)) << 3))

// ---------------- LayerNorm: fp32 in, bf16 out ----------------
__global__ __launch_bounds__(256) void ln_kernel(const float* __restrict__ x,
                                                 const float* __restrict__ gw,
                                                 const float* __restrict__ bw,
                                                 unsigned short* __restrict__ y)
{
    int row = blockIdx.x;
    int t = threadIdx.x;
    const float* xr = x + (size_t)row * HDIM;
    float4 v = *(const float4*)(xr + t * 4);
    float s1 = v.x + v.y + v.z + v.w;
    float s2 = v.x * v.x + v.y * v.y + v.z * v.z + v.w * v.w;
#pragma unroll
    for (int m = 1; m < 64; m <<= 1) {
        s1 += __shfl_xor(s1, m);
        s2 += __shfl_xor(s2, m);
    }
    __shared__ float red[8];
    int wid = t >> 6;
    if ((t & 63) == 0) { red[wid * 2] = s1; red[wid * 2 + 1] = s2; }
    __syncthreads();
    if (t == 0) {
        float a = red[0] + red[2] + red[4] + red[6];
        float b = red[1] + red[3] + red[5] + red[7];
        red[0] = a; red[1] = b;
    }
    __syncthreads();
    float mu  = red[0] * (1.0f / HDIM);
    float var = red[1] * (1.0f / HDIM) - mu * mu;
    float rs  = rsqrtf(var + 1e-5f);
    float4 g4 = *(const float4*)(gw + t * 4);
    float4 b4 = *(const float4*)(bw + t * 4);
    ushort4 o;
    o.x = f2bf((v.x - mu) * rs * g4.x + b4.x);
    o.y = f2bf((v.y - mu) * rs * g4.y + b4.y);
    o.z = f2bf((v.z - mu) * rs * g4.z + b4.z);
    o.w = f2bf((v.w - mu) * rs * g4.w + b4.w);
    *(ushort4*)(y + (size_t)row * HDIM + t * 4) = o;
}

// ------- batched weight fp32 [K][N] -> bf16 transposed [N][K], all 4 weights -------
// block ranges: [0,3072) Wqkv  [3072,4096) Wout  [4096,8192) W1  [8192,12288) W2
__global__ __launch_bounds__(256) void wconv_all(const float* __restrict__ Wq,
                                                 const float* __restrict__ Wo,
                                                 const float* __restrict__ W1,
                                                 const float* __restrict__ W2,
                                                 unsigned short* __restrict__ WqT,
                                                 unsigned short* __restrict__ WoT,
                                                 unsigned short* __restrict__ W1T,
                                                 unsigned short* __restrict__ W2T)
{
    int bid = blockIdx.x;
    const float* W; unsigned short* WT; int K, nx, idx;
    if (bid < 3072)      { W = Wq; WT = WqT; K = 1024; nx = 96;  idx = bid; }
    else if (bid < 4096) { W = Wo; WT = WoT; K = 1024; nx = 32;  idx = bid - 3072; }
    else if (bid < 8192) { W = W1; WT = W1T; K = 1024; nx = 128; idx = bid - 4096; }
    else                 { W = W2; WT = W2T; K = 4096; nx = 32;  idx = bid - 8192; }
    int N = nx * 32;
    int n0 = (idx % nx) * 32, k0 = (idx / nx) * 32;

    __shared__ float tile[32][33];
    int t = threadIdx.x, c = t & 31, r = t >> 5;
#pragma unroll
    for (int i = 0; i < 4; ++i)
        tile[r + 8 * i][c] = W[(size_t)(k0 + r + 8 * i) * N + n0 + c];
    __syncthreads();
#pragma unroll
    for (int i = 0; i < 4; ++i)
        WT[(size_t)(n0 + r + 8 * i) * K + k0 + c] = f2bf(tile[c][r + 8 * i]);
}

// ------------- MFMA GEMM: C[M,N] = A[M,K] @ BT[N,K]^T + bias (+EPI) -------------
// 128x128 tile, BK=64, double-buffered LDS (2x32KB), prefetch-before-compute,
// one barrier per K-tile (round-1 verified best; 0 bank conflicts).
template <int EPI>
__global__ __launch_bounds__(256, 2) void mgemm(const unsigned short* __restrict__ A,
                                                const unsigned short* __restrict__ BT,
                                                const float* __restrict__ bias,
                                                const float* __restrict__ resid,
                                                float* __restrict__ Cf,
                                                unsigned short* __restrict__ Cb,
                                                int M, int N, int K)
{
    __shared__ char smem[65536];   // [2 bufs][A 16KB | B 16KB]
    int t = threadIdx.x;
    int bn = blockIdx.x * 128, bm = blockIdx.y * 128;
    int l = t & 63, w = t >> 6;
    int wm = w >> 1, wn = w & 1;
    int lrow = l & 15, kq = l >> 4;

    f32x4 acc[4][4];
#pragma unroll
    for (int i = 0; i < 4; ++i)
#pragma unroll
        for (int j = 0; j < 4; ++j) acc[i][j] = {0.f, 0.f, 0.f, 0.f};

    const unsigned short* Ap[4];
    const unsigned short* Bp[4];
    int ld[4];
#pragma unroll
    for (int i = 0; i < 4; ++i) {
        int cid = i * 256 + t;
        int row = cid >> 3, c = cid & 7;
        int gc = (c ^ (row & 7)) << 3;
        Ap[i] = A + (size_t)(bm + row) * K + gc;
        Bp[i] = BT + (size_t)(bn + row) * K + gc;
        ld[i] = cid << 4;
    }

    int nt = K >> 6;
#pragma unroll
    for (int i = 0; i < 4; ++i) {
        gld16(smem + ld[i], Ap[i]);
        gld16(smem + 16384 + ld[i], Bp[i]);
    }
    __syncthreads();

    for (int tk = 0; tk < nt; ++tk) {
        int cur = (tk & 1) << 15;
        if (tk + 1 < nt) {
            int k0 = (tk + 1) << 6;
            int nxt = 32768 - cur;
#pragma unroll
            for (int i = 0; i < 4; ++i) {
                gld16(smem + nxt + ld[i], Ap[i] + k0);
                gld16(smem + nxt + 16384 + ld[i], Bp[i] + k0);
            }
        }
        const unsigned short* sA = (const unsigned short*)(smem + cur);
        const unsigned short* sB = (const unsigned short*)(smem + cur + 16384);
#pragma unroll
        for (int kk = 0; kk < 2; ++kk) {
            bf16x8 af[4], bv[4];
#pragma unroll
            for (int mi = 0; mi < 4; ++mi)
                af[mi] = *(const bf16x8*)(sA + SWZ(wm * 64 + mi * 16 + lrow, kk * 4 + kq));
#pragma unroll
            for (int ni = 0; ni < 4; ++ni)
                bv[ni] = *(const bf16x8*)(sB + SWZ(wn * 64 + ni * 16 + lrow, kk * 4 + kq));
#pragma unroll
            for (int mi = 0; mi < 4; ++mi)
#pragma unroll
                for (int ni = 0; ni < 4; ++ni)
                    acc[mi][ni] = __builtin_amdgcn_mfma_f32_16x16x32_bf16(af[mi], bv[ni], acc[mi][ni], 0, 0, 0);
        }
        __syncthreads();
    }

    int crow = (l >> 4) * 4;
    int ccol = l & 15;
#pragma unroll
    for (int mi = 0; mi < 4; ++mi) {
#pragma unroll
        for (int ni = 0; ni < 4; ++ni) {
            int gcol = bn + wn * 64 + ni * 16 + ccol;
            float bv = bias[gcol];
#pragma unroll
            for (int r = 0; r < 4; ++r) {
                int grow = bm + wm * 64 + mi * 16 + crow + r;
                size_t off = (size_t)grow * N + gcol;
                float v = acc[mi][ni][r] + bv;
                if (EPI == 1) {
                    Cf[off] = v + resid[off];
                } else if (EPI == 2) {
                    v = 0.5f * v * (1.0f + erff(v * 0.70710678118654752f));
                    Cb[off] = f2bf(v);
                } else {
                    Cb[off] = f2bf(v);
                }
            }
        }
    }
}

// ---------------- MFMA flash attention v3: 128 q-rows / 8 waves per block ----------------
// Same per-wave algorithm as v2 (swapped QK^T, in-reg softmax, defer-max, XOR
// swizzle, reg-staged K/V prefetch across raw s_barrier).  Amortization change
// only: 2x q-rows per block -> per-thread K/V staging work per tile halves,
// K/V global traffic halves (512 blocks), 16 waves/CU (LDS 64KB, 2 blocks/CU,
// grid 512 = exactly 2 blocks/CU).
__global__ __launch_bounds__(512) void mattn(const unsigned short* __restrict__ qkv,
                                             unsigned short* __restrict__ out)
{
    __shared__ unsigned short Qs[128 * 64];       // [q][d] swizzled (16KB)
    __shared__ unsigned short Ks[2][64 * 64];     // [k][d] swizzled, dbuf (16KB)
    __shared__ unsigned short Vt[2][64 * 64];     // [d][k] swizzled, dbuf (16KB)
    __shared__ unsigned short Ps[8 * 16 * 64];    // per-wave [q16][k64] swizzled (16KB)
    int t = threadIdx.x;
    int w = t >> 6, l = t & 63;
    int lr = l & 15, lh = l >> 4;
    int q0 = blockIdx.x * 128;
    int hh = blockIdx.y, b = blockIdx.z;
    const unsigned short* Qg = qkv + (size_t)b * SEQ * 3072 + hh * 64;
    const unsigned short* Kg = Qg + 1024;
    const unsigned short* Vg = Qg + 2048;

    // ---- stage Q via gld16 (pre-swizzled global source): 1024 chunks, 2/thread ----
#pragma unroll
    for (int i = 0; i < 2; ++i) {
        int chunkid = i * 512 + t;
        int row = chunkid >> 3, c = chunkid & 7;
        gld16(((char*)Qs) + chunkid * 16,
              Qg + (size_t)(q0 + row) * 3072 + ((c ^ (row & 7)) << 3));
    }

    // ---- K reg-staging: 512 chunks (64 rows x 8), 1 per thread ----
    int kr0 = t >> 3, kc0 = t & 7;
    const unsigned short* Kp0 = Kg + (size_t)kr0 * 3072 + kc0 * 8;
    int kd0 = SWZ(kr0, kc0);
    // ---- V: thread handles k-pair (vk,vk+1) x 4 d-elems ----
    int vk = (t & 31) * 2;
    int vd0 = ((t >> 5) & 15) * 4;
    const unsigned short* Vp0 = Vg + (size_t)vk * 3072 + vd0;
    const unsigned short* Vp1 = Vp0 + 3072;

    // prologue: load K/V tile 0 to regs
    u16x8 k0 = *(const u16x8*)Kp0;
    u16x4 v0 = *(const u16x4*)Vp0;
    u16x4 v1 = *(const u16x4*)Vp1;
    Kp0 += 64 * 3072; Vp0 += 64 * 3072; Vp1 += 64 * 3072;

    __syncthreads();   // Qs ready (full drain; prologue only)
    bf16x8 qa[2];
#pragma unroll
    for (int ks = 0; ks < 2; ++ks)
        qa[ks] = *(const bf16x8*)(Qs + SWZ(w * 16 + lr, ks * 4 + lh));

    // write tile 0 into buffer 0
    *(u16x8*)(Ks[0] + kd0) = k0;
#pragma unroll
    for (int j = 0; j < 4; ++j) {
        int d = vd0 + j;
        unsigned pack = (unsigned)(unsigned short)v0[j] | ((unsigned)(unsigned short)v1[j] << 16);
        *(unsigned*)(Vt[0] + SWZ(d, vk >> 3) + (vk & 7)) = pack;
    }
    // prefetch tile 1 to regs (stays in flight across the raw barrier)
    k0 = *(const u16x8*)Kp0;
    v0 = *(const u16x4*)Vp0; v1 = *(const u16x4*)Vp1;
    Kp0 += 64 * 3072; Vp0 += 64 * 3072; Vp1 += 64 * 3072;
    asm volatile("s_waitcnt lgkmcnt(0)" ::: "memory");   // publish buf0 writes
    __builtin_amdgcn_s_barrier();

    f32x4 o[4];
#pragma unroll
    for (int i = 0; i < 4; ++i) o[i] = {0.f, 0.f, 0.f, 0.f};
    float mr = -3.0e38f, lsum = 0.f;   // per-lane: q-row = w*16 + lr
    unsigned short* Pw = Ps + w * (16 * 64);
    const float C = 0.18033688011112042f;  // 0.125 * log2(e)

    const int nt = SEQ / 64;   // 32
    for (int tt = 0; tt < nt; ++tt) {
        const unsigned short* Kc = Ks[tt & 1];
        const unsigned short* Vc = Vt[tt & 1];

        // swapped QK^T: S^T = K·Q^T -> lane holds q=lr, k=ni*16+lh*4+r
        f32x4 s[4];
#pragma unroll
        for (int ni = 0; ni < 4; ++ni) s[ni] = {0.f, 0.f, 0.f, 0.f};
#pragma unroll
        for (int ks = 0; ks < 2; ++ks) {
#pragma unroll
            for (int ni = 0; ni < 4; ++ni) {
                bf16x8 kb = *(const bf16x8*)(Kc + SWZ(ni * 16 + lr, ks * 4 + lh));
                s[ni] = __builtin_amdgcn_mfma_f32_16x16x32_bf16(kb, qa[ks], s[ni], 0, 0, 0);
            }
        }
        // row max: 15 in-reg + 2 shfl (lanes sharing lr)
        float mx = s[0][0];
#pragma unroll
        for (int ni = 0; ni < 4; ++ni)
#pragma unroll
            for (int r = 0; r < 4; ++r) mx = fmaxf(mx, s[ni][r]);
        mx = fmaxf(mx, __shfl_xor(mx, 16));
        mx = fmaxf(mx, __shfl_xor(mx, 32));
        // defer-max: only rescale when growth beyond e^8 bound (always on tile 0)
        if (__any(mx > mr + 64.0f)) {
            float mn = fmaxf(mr, mx);
            float corr = fexp2((mr - mn) * C);
            mr = mn;
            lsum *= corr;
            float cr[4];
#pragma unroll
            for (int r = 0; r < 4; ++r) cr[r] = __shfl(corr, lh * 4 + r, 16);
#pragma unroll
            for (int nd = 0; nd < 4; ++nd) {
                o[nd][0] *= cr[0]; o[nd][1] *= cr[1];
                o[nd][2] *= cr[2]; o[nd][3] *= cr[3];
            }
        }
        float mc = mr * C;
        float rsum = 0.f;
#pragma unroll
        for (int ni = 0; ni < 4; ++ni)
#pragma unroll
            for (int r = 0; r < 4; ++r) {
                float p = fexp2(fmaf(s[ni][r], C, -mc));
                s[ni][r] = p;
                rsum += p;
            }
        rsum += __shfl_xor(rsum, 16);
        rsum += __shfl_xor(rsum, 32);
        lsum += rsum;
        // P write: packed pairs (adjacent k = r, r+1)
#pragma unroll
        for (int ni = 0; ni < 4; ++ni)
#pragma unroll
            for (int rp = 0; rp < 2; ++rp) {
                int k = ni * 16 + lh * 4 + rp * 2;
                *(unsigned*)(Pw + SWZ(lr, k >> 3) + (k & 7)) =
                    pk2bf(s[ni][rp * 2], s[ni][rp * 2 + 1]);
            }
        // PV: O[q16][d64] += P[q16][k64] @ V[k64][d64]
#pragma unroll
        for (int ks = 0; ks < 2; ++ks) {
            bf16x8 pa = *(const bf16x8*)(Pw + SWZ(lr, ks * 4 + lh));
#pragma unroll
            for (int nd = 0; nd < 4; ++nd) {
                bf16x8 vb = *(const bf16x8*)(Vc + SWZ(nd * 16 + lr, ks * 4 + lh));
                o[nd] = __builtin_amdgcn_mfma_f32_16x16x32_bf16(pa, vb, o[nd], 0, 0, 0);
            }
        }

        // ---- post-compute: write next tile's K/V (regs -> LDS), prefetch t+2 ----
        if (tt + 1 < nt) {
            int nb = (tt & 1) ^ 1;
            // implicit vmcnt wait here covers loads issued one full tile ago
            *(u16x8*)(Ks[nb] + kd0) = k0;
#pragma unroll
            for (int j = 0; j < 4; ++j) {
                int d = vd0 + j;
                unsigned pack = (unsigned)(unsigned short)v0[j] | ((unsigned)(unsigned short)v1[j] << 16);
                *(unsigned*)(Vt[nb] + SWZ(d, vk >> 3) + (vk & 7)) = pack;
            }
            if (tt + 2 < nt) {
                k0 = *(const u16x8*)Kp0;
                v0 = *(const u16x4*)Vp0; v1 = *(const u16x4*)Vp1;
                Kp0 += 64 * 3072; Vp0 += 64 * 3072; Vp1 += 64 * 3072;
            }
            asm volatile("s_waitcnt lgkmcnt(0)" ::: "memory");  // publish nb writes
            __builtin_amdgcn_s_barrier();                        // raw: no vmcnt drain
        }
    }
    // epilogue: redistribute 1/lsum to PV row owners
    float inv = 1.0f / lsum;
    float ir[4];
#pragma unroll
    for (int r = 0; r < 4; ++r) ir[r] = __shfl(inv, lh * 4 + r, 16);
#pragma unroll
    for (int r = 0; r < 4; ++r) {
        int q = q0 + w * 16 + lh * 4 + r;
#pragma unroll
        for (int nd = 0; nd < 4; ++nd) {
            int d = nd * 16 + lr;
            out[(size_t)((size_t)b * SEQ + q) * HDIM + hh * 64 + d] = f2bf(o[nd][r] * ir[r]);
        }
    }
}

extern "C" void kernel_launch(void* const* d_in, const int* in_sizes, int n_in,
                              void* d_out, int out_size, void* d_ws, size_t ws_size,
                              hipStream_t stream)
{
    const float* x     = (const float*)d_in[0];
    const float* ln1_g = (const float*)d_in[1];
    const float* ln1_b = (const float*)d_in[2];
    const float* W_qkv = (const float*)d_in[3];
    const float* b_qkv = (const float*)d_in[4];
    const float* W_out = (const float*)d_in[5];
    const float* b_out = (const float*)d_in[6];
    const float* ln2_g = (const float*)d_in[7];
    const float* ln2_b = (const float*)d_in[8];
    const float* W1    = (const float*)d_in[9];
    const float* b1    = (const float*)d_in[10];
    const float* W2    = (const float*)d_in[11];
    const float* b2    = (const float*)d_in[12];
    float* out = (float*)d_out;
    char* ws8  = (char*)d_ws;

    const int M = BATCH * SEQ;  // 4096
    const size_t MB = 1048576;

    unsigned short* hbuf = (unsigned short*)(ws8);
    unsigned short* qkvb = (unsigned short*)(ws8 + 8 * MB);
    unsigned short* attb = (unsigned short*)(ws8 + 32 * MB);
    unsigned short* ffn1 = (unsigned short*)(ws8 + 8 * MB);
    unsigned short* WqT  = (unsigned short*)(ws8 + 40 * MB);
    unsigned short* WoT  = (unsigned short*)(ws8 + 46 * MB);
    unsigned short* W1T  = (unsigned short*)(ws8 + 48 * MB);
    unsigned short* W2T  = (unsigned short*)(ws8 + 56 * MB);

    // all 4 weight conversions in one launch (12288 blocks)
    wconv_all<<<12288, 256, 0, stream>>>(W_qkv, W_out, W1, W2, WqT, WoT, W1T, W2T);

    ln_kernel<<<M, 256, 0, stream>>>(x, ln1_g, ln1_b, hbuf);
    mgemm<0><<<dim3(3 * HDIM / 128, M / 128), 256, 0, stream>>>(hbuf, WqT, b_qkv, nullptr, nullptr, qkvb, M, 3 * HDIM, HDIM);
    mattn<<<dim3(SEQ / 128, NHEAD, BATCH), 512, 0, stream>>>(qkvb, attb);
    mgemm<1><<<dim3(HDIM / 128, M / 128), 256, 0, stream>>>(attb, WoT, b_out, x, out, nullptr, M, HDIM, HDIM);
    ln_kernel<<<M, 256, 0, stream>>>(out, ln2_g, ln2_b, hbuf);
    mgemm<2><<<dim3(4 * HDIM / 128, M / 128), 256, 0, stream>>>(hbuf, W1T, b1, nullptr, nullptr, ffn1, M, 4 * HDIM, HDIM);
    mgemm<1><<<dim3(HDIM / 128, M / 128), 256, 0, stream>>>(ffn1, W2T, b2, out, out, nullptr, M, HDIM, 4 * HDIM);
}

// Round 7
// 226.177 us; speedup vs baseline: 1.2931x; 1.0270x over previous
//
#include <hip/hip_runtime.h>
#include <hip/hip_bf16.h>
#include <math.h>

#define HDIM 1024
#define SEQ  2048
#define BATCH 2
#define NHEAD 16
#define HEADD 64

typedef short bf16x8 __attribute__((ext_vector_type(8)));
typedef float f32x4  __attribute__((ext_vector_type(4)));
typedef unsigned short u16x8 __attribute__((ext_vector_type(8)));
typedef unsigned short u16x4 __attribute__((ext_vector_type(4)));

__device__ __forceinline__ unsigned short f2bf(float f) {
    unsigned u = __float_as_uint(f);
    unsigned r = (u + 0x7FFFu + ((u >> 16) & 1u)) >> 16;
    return (unsigned short)r;
}
__device__ __forceinline__ float b2f(unsigned short s) {
    return __uint_as_float(((unsigned)s) << 16);
}
__device__ __forceinline__ unsigned pk2bf(float lo, float hi) {
    __hip_bfloat162 h = __float22bfloat162_rn(float2{lo, hi});
    unsigned r;
    __builtin_memcpy(&r, &h, 4);
    return r;
}
__device__ __forceinline__ float fexp2(float x) {
#if __has_builtin(__builtin_amdgcn_exp2f)
    return __builtin_amdgcn_exp2f(x);
#else
    return exp2f(x);
#endif
}
__device__ __forceinline__ void gld16(void* lds, const void* g) {
    __builtin_amdgcn_global_load_lds(
        (const __attribute__((address_space(1))) unsigned int*)(g),
        (__attribute__((address_space(3))) unsigned int*)(lds),
        16, 0, 0);
}

// swizzled element offset for row-major [*][64] bf16 tiles (128B rows, 8 chunks of 16B)
#define SWZ(row, chunk) (((row) * 64) + (((chunk) ^ ((row) & 7)) << 3))

// T1: XCD-aware bijective chunked remap (hw dispatch id -> logical block id).
// HW round-robins consecutive ids across 8 XCDs; remap gives each XCD a
// CONTIGUOUS logical chunk so neighbor blocks (sharing operand panels) hit
// the same per-XCD L2.  Requires nwg % 8 == 0 (all our grids comply).
__device__ __forceinline__ void xcd_remap(int& bx, int& by) {
    int nx = gridDim.x, nwg = nx * gridDim.y;
    int hwid = by * nx + bx;
    int lid = (hwid & 7) * (nwg >> 3) + (hwid >> 3);
    bx = lid % nx;
    by = lid / nx;
}

// ---------------- LayerNorm: fp32 in, bf16 out ----------------
__global__ __launch_bounds__(256) void ln_kernel(const float* __restrict__ x,
                                                 const float* __restrict__ gw,
                                                 const float* __restrict__ bw,
                                                 unsigned short* __restrict__ y)
{
    int row = blockIdx.x;
    int t = threadIdx.x;
    const float* xr = x + (size_t)row * HDIM;
    float4 v = *(const float4*)(xr + t * 4);
    float s1 = v.x + v.y + v.z + v.w;
    float s2 = v.x * v.x + v.y * v.y + v.z * v.z + v.w * v.w;
#pragma unroll
    for (int m = 1; m < 64; m <<= 1) {
        s1 += __shfl_xor(s1, m);
        s2 += __shfl_xor(s2, m);
    }
    __shared__ float red[8];
    int wid = t >> 6;
    if ((t & 63) == 0) { red[wid * 2] = s1; red[wid * 2 + 1] = s2; }
    __syncthreads();
    if (t == 0) {
        float a = red[0] + red[2] + red[4] + red[6];
        float b = red[1] + red[3] + red[5] + red[7];
        red[0] = a; red[1] = b;
    }
    __syncthreads();
    float mu  = red[0] * (1.0f / HDIM);
    float var = red[1] * (1.0f / HDIM) - mu * mu;
    float rs  = rsqrtf(var + 1e-5f);
    float4 g4 = *(const float4*)(gw + t * 4);
    float4 b4 = *(const float4*)(bw + t * 4);
    ushort4 o;
    o.x = f2bf((v.x - mu) * rs * g4.x + b4.x);
    o.y = f2bf((v.y - mu) * rs * g4.y + b4.y);
    o.z = f2bf((v.z - mu) * rs * g4.z + b4.z);
    o.w = f2bf((v.w - mu) * rs * g4.w + b4.w);
    *(ushort4*)(y + (size_t)row * HDIM + t * 4) = o;
}

// ------- batched weight fp32 [K][N] -> bf16 transposed [N][K], all 4 weights -------
__global__ __launch_bounds__(256) void wconv_all(const float* __restrict__ Wq,
                                                 const float* __restrict__ Wo,
                                                 const float* __restrict__ W1,
                                                 const float* __restrict__ W2,
                                                 unsigned short* __restrict__ WqT,
                                                 unsigned short* __restrict__ WoT,
                                                 unsigned short* __restrict__ W1T,
                                                 unsigned short* __restrict__ W2T)
{
    int bid = blockIdx.x;
    const float* W; unsigned short* WT; int K, nx, idx;
    if (bid < 3072)      { W = Wq; WT = WqT; K = 1024; nx = 96;  idx = bid; }
    else if (bid < 4096) { W = Wo; WT = WoT; K = 1024; nx = 32;  idx = bid - 3072; }
    else if (bid < 8192) { W = W1; WT = W1T; K = 1024; nx = 128; idx = bid - 4096; }
    else                 { W = W2; WT = W2T; K = 4096; nx = 32;  idx = bid - 8192; }
    int N = nx * 32;
    int n0 = (idx % nx) * 32, k0 = (idx / nx) * 32;

    __shared__ float tile[32][33];
    int t = threadIdx.x, c = t & 31, r = t >> 5;
#pragma unroll
    for (int i = 0; i < 4; ++i)
        tile[r + 8 * i][c] = W[(size_t)(k0 + r + 8 * i) * N + n0 + c];
    __syncthreads();
#pragma unroll
    for (int i = 0; i < 4; ++i)
        WT[(size_t)(n0 + r + 8 * i) * K + k0 + c] = f2bf(tile[c][r + 8 * i]);
}

// ------------- MFMA GEMM 128x128: BK=64, dbuf LDS 64KB, 1 barrier/K-tile -------------
// (round-1 verified best structure; 0 bank conflicts) + T1 XCD remap.
template <int EPI>
__global__ __launch_bounds__(256, 2) void mgemm(const unsigned short* __restrict__ A,
                                                const unsigned short* __restrict__ BT,
                                                const float* __restrict__ bias,
                                                const float* __restrict__ resid,
                                                float* __restrict__ Cf,
                                                unsigned short* __restrict__ Cb,
                                                int M, int N, int K)
{
    __shared__ char smem[65536];   // [2 bufs][A 16KB | B 16KB]
    int t = threadIdx.x;
    int bx = blockIdx.x, by = blockIdx.y;
    xcd_remap(bx, by);
    int bn = bx * 128, bm = by * 128;
    int l = t & 63, w = t >> 6;
    int wm = w >> 1, wn = w & 1;
    int lrow = l & 15, kq = l >> 4;

    f32x4 acc[4][4];
#pragma unroll
    for (int i = 0; i < 4; ++i)
#pragma unroll
        for (int j = 0; j < 4; ++j) acc[i][j] = {0.f, 0.f, 0.f, 0.f};

    const unsigned short* Ap[4];
    const unsigned short* Bp[4];
    int ld[4];
#pragma unroll
    for (int i = 0; i < 4; ++i) {
        int cid = i * 256 + t;
        int row = cid >> 3, c = cid & 7;
        int gc = (c ^ (row & 7)) << 3;
        Ap[i] = A + (size_t)(bm + row) * K + gc;
        Bp[i] = BT + (size_t)(bn + row) * K + gc;
        ld[i] = cid << 4;
    }

    int nt = K >> 6;
#pragma unroll
    for (int i = 0; i < 4; ++i) {
        gld16(smem + ld[i], Ap[i]);
        gld16(smem + 16384 + ld[i], Bp[i]);
    }
    __syncthreads();

    for (int tk = 0; tk < nt; ++tk) {
        int cur = (tk & 1) << 15;
        if (tk + 1 < nt) {
            int k0 = (tk + 1) << 6;
            int nxt = 32768 - cur;
#pragma unroll
            for (int i = 0; i < 4; ++i) {
                gld16(smem + nxt + ld[i], Ap[i] + k0);
                gld16(smem + nxt + 16384 + ld[i], Bp[i] + k0);
            }
        }
        const unsigned short* sA = (const unsigned short*)(smem + cur);
        const unsigned short* sB = (const unsigned short*)(smem + cur + 16384);
#pragma unroll
        for (int kk = 0; kk < 2; ++kk) {
            bf16x8 af[4], bv[4];
#pragma unroll
            for (int mi = 0; mi < 4; ++mi)
                af[mi] = *(const bf16x8*)(sA + SWZ(wm * 64 + mi * 16 + lrow, kk * 4 + kq));
#pragma unroll
            for (int ni = 0; ni < 4; ++ni)
                bv[ni] = *(const bf16x8*)(sB + SWZ(wn * 64 + ni * 16 + lrow, kk * 4 + kq));
#pragma unroll
            for (int mi = 0; mi < 4; ++mi)
#pragma unroll
                for (int ni = 0; ni < 4; ++ni)
                    acc[mi][ni] = __builtin_amdgcn_mfma_f32_16x16x32_bf16(af[mi], bv[ni], acc[mi][ni], 0, 0, 0);
        }
        __syncthreads();
    }

    int crow = (l >> 4) * 4;
    int ccol = l & 15;
#pragma unroll
    for (int mi = 0; mi < 4; ++mi) {
#pragma unroll
        for (int ni = 0; ni < 4; ++ni) {
            int gcol = bn + wn * 64 + ni * 16 + ccol;
            float bv = bias[gcol];
#pragma unroll
            for (int r = 0; r < 4; ++r) {
                int grow = bm + wm * 64 + mi * 16 + crow + r;
                size_t off = (size_t)grow * N + gcol;
                float v = acc[mi][ni][r] + bv;
                if (EPI == 1) {
                    Cf[off] = v + resid[off];
                } else if (EPI == 2) {
                    v = 0.5f * v * (1.0f + erff(v * 0.70710678118654752f));
                    Cb[off] = f2bf(v);
                } else {
                    Cb[off] = f2bf(v);
                }
            }
        }
    }
}

// ------------- MFMA GEMM 64x128: same template geometry-halved in M -------------
// For N=1024 shapes: grid (8, M/64) = 512 blocks -> 2 blocks/CU (was 256 = 1/CU;
// the 2-phase structure relies on inter-block wave overlap for latency hiding).
// LDS = 2 x (A 8KB + B 16KB) = 48KB.  Same sync edges / swizzle / staging idiom.
template <int EPI>
__global__ __launch_bounds__(256, 2) void mgemm64(const unsigned short* __restrict__ A,
                                                  const unsigned short* __restrict__ BT,
                                                  const float* __restrict__ bias,
                                                  const float* __restrict__ resid,
                                                  float* __restrict__ Cf,
                                                  unsigned short* __restrict__ Cb,
                                                  int M, int N, int K)
{
    __shared__ char smem[49152];   // [2 bufs][A 8KB | B 16KB]
    int t = threadIdx.x;
    int bx = blockIdx.x, by = blockIdx.y;
    xcd_remap(bx, by);
    int bn = bx * 128, bm = by * 64;
    int l = t & 63, w = t >> 6;       // 4 waves: 1M x 4N; per-wave C = 64x32
    int lrow = l & 15, kq = l >> 4;

    f32x4 acc[4][2];
#pragma unroll
    for (int i = 0; i < 4; ++i)
#pragma unroll
        for (int j = 0; j < 2; ++j) acc[i][j] = {0.f, 0.f, 0.f, 0.f};

    // staging: A = 64 rows x 8 chunks = 512 chunks (2/thread); B = 1024 (4/thread)
    const unsigned short* Ap[2];
    int ldA[2];
#pragma unroll
    for (int i = 0; i < 2; ++i) {
        int cid = i * 256 + t;
        int row = cid >> 3, c = cid & 7;
        Ap[i] = A + (size_t)(bm + row) * K + ((c ^ (row & 7)) << 3);
        ldA[i] = cid << 4;
    }
    const unsigned short* Bp[4];
    int ldB[4];
#pragma unroll
    for (int i = 0; i < 4; ++i) {
        int cid = i * 256 + t;
        int row = cid >> 3, c = cid & 7;
        Bp[i] = BT + (size_t)(bn + row) * K + ((c ^ (row & 7)) << 3);
        ldB[i] = cid << 4;
    }

    int nt = K >> 6;
#pragma unroll
    for (int i = 0; i < 2; ++i) gld16(smem + ldA[i], Ap[i]);
#pragma unroll
    for (int i = 0; i < 4; ++i) gld16(smem + 8192 + ldB[i], Bp[i]);
    __syncthreads();

    for (int tk = 0; tk < nt; ++tk) {
        int cur = (tk & 1) * 24576;
        if (tk + 1 < nt) {
            int k0 = (tk + 1) << 6;
            int nxt = 24576 - cur;
#pragma unroll
            for (int i = 0; i < 2; ++i) gld16(smem + nxt + ldA[i], Ap[i] + k0);
#pragma unroll
            for (int i = 0; i < 4; ++i) gld16(smem + nxt + 8192 + ldB[i], Bp[i] + k0);
        }
        const unsigned short* sA = (const unsigned short*)(smem + cur);
        const unsigned short* sB = (const unsigned short*)(smem + cur + 8192);
#pragma unroll
        for (int kk = 0; kk < 2; ++kk) {
            bf16x8 af[4], bv[2];
#pragma unroll
            for (int mi = 0; mi < 4; ++mi)
                af[mi] = *(const bf16x8*)(sA + SWZ(mi * 16 + lrow, kk * 4 + kq));
#pragma unroll
            for (int ni = 0; ni < 2; ++ni)
                bv[ni] = *(const bf16x8*)(sB + SWZ(w * 32 + ni * 16 + lrow, kk * 4 + kq));
#pragma unroll
            for (int mi = 0; mi < 4; ++mi)
#pragma unroll
                for (int ni = 0; ni < 2; ++ni)
                    acc[mi][ni] = __builtin_amdgcn_mfma_f32_16x16x32_bf16(af[mi], bv[ni], acc[mi][ni], 0, 0, 0);
        }
        __syncthreads();
    }

    int crow = (l >> 4) * 4;
    int ccol = l & 15;
#pragma unroll
    for (int mi = 0; mi < 4; ++mi) {
#pragma unroll
        for (int ni = 0; ni < 2; ++ni) {
            int gcol = bn + w * 32 + ni * 16 + ccol;
            float bv = bias[gcol];
#pragma unroll
            for (int r = 0; r < 4; ++r) {
                int grow = bm + mi * 16 + crow + r;
                size_t off = (size_t)grow * N + gcol;
                float v = acc[mi][ni][r] + bv;
                if (EPI == 1) {
                    Cf[off] = v + resid[off];
                } else if (EPI == 2) {
                    v = 0.5f * v * (1.0f + erff(v * 0.70710678118654752f));
                    Cb[off] = f2bf(v);
                } else {
                    Cb[off] = f2bf(v);
                }
            }
        }
    }
}

// ---------------- MFMA flash attention v3: 128 q-rows / 8 waves per block ----------------
__global__ __launch_bounds__(512) void mattn(const unsigned short* __restrict__ qkv,
                                             unsigned short* __restrict__ out)
{
    __shared__ unsigned short Qs[128 * 64];       // [q][d] swizzled (16KB)
    __shared__ unsigned short Ks[2][64 * 64];     // [k][d] swizzled, dbuf (16KB)
    __shared__ unsigned short Vt[2][64 * 64];     // [d][k] swizzled, dbuf (16KB)
    __shared__ unsigned short Ps[8 * 16 * 64];    // per-wave [q16][k64] swizzled (16KB)
    int t = threadIdx.x;
    int w = t >> 6, l = t & 63;
    int lr = l & 15, lh = l >> 4;
    int q0 = blockIdx.x * 128;
    int hh = blockIdx.y, b = blockIdx.z;
    const unsigned short* Qg = qkv + (size_t)b * SEQ * 3072 + hh * 64;
    const unsigned short* Kg = Qg + 1024;
    const unsigned short* Vg = Qg + 2048;

    // ---- stage Q via gld16 (pre-swizzled global source): 1024 chunks, 2/thread ----
#pragma unroll
    for (int i = 0; i < 2; ++i) {
        int chunkid = i * 512 + t;
        int row = chunkid >> 3, c = chunkid & 7;
        gld16(((char*)Qs) + chunkid * 16,
              Qg + (size_t)(q0 + row) * 3072 + ((c ^ (row & 7)) << 3));
    }

    // ---- K reg-staging: 512 chunks (64 rows x 8), 1 per thread ----
    int kr0 = t >> 3, kc0 = t & 7;
    const unsigned short* Kp0 = Kg + (size_t)kr0 * 3072 + kc0 * 8;
    int kd0 = SWZ(kr0, kc0);
    // ---- V: thread handles k-pair (vk,vk+1) x 4 d-elems ----
    int vk = (t & 31) * 2;
    int vd0 = ((t >> 5) & 15) * 4;
    const unsigned short* Vp0 = Vg + (size_t)vk * 3072 + vd0;
    const unsigned short* Vp1 = Vp0 + 3072;

    // prologue: load K/V tile 0 to regs
    u16x8 k0 = *(const u16x8*)Kp0;
    u16x4 v0 = *(const u16x4*)Vp0;
    u16x4 v1 = *(const u16x4*)Vp1;
    Kp0 += 64 * 3072; Vp0 += 64 * 3072; Vp1 += 64 * 3072;

    __syncthreads();   // Qs ready (full drain; prologue only)
    bf16x8 qa[2];
#pragma unroll
    for (int ks = 0; ks < 2; ++ks)
        qa[ks] = *(const bf16x8*)(Qs + SWZ(w * 16 + lr, ks * 4 + lh));

    // write tile 0 into buffer 0
    *(u16x8*)(Ks[0] + kd0) = k0;
#pragma unroll
    for (int j = 0; j < 4; ++j) {
        int d = vd0 + j;
        unsigned pack = (unsigned)(unsigned short)v0[j] | ((unsigned)(unsigned short)v1[j] << 16);
        *(unsigned*)(Vt[0] + SWZ(d, vk >> 3) + (vk & 7)) = pack;
    }
    // prefetch tile 1 to regs (stays in flight across the raw barrier)
    k0 = *(const u16x8*)Kp0;
    v0 = *(const u16x4*)Vp0; v1 = *(const u16x4*)Vp1;
    Kp0 += 64 * 3072; Vp0 += 64 * 3072; Vp1 += 64 * 3072;
    asm volatile("s_waitcnt lgkmcnt(0)" ::: "memory");   // publish buf0 writes
    __builtin_amdgcn_s_barrier();

    f32x4 o[4];
#pragma unroll
    for (int i = 0; i < 4; ++i) o[i] = {0.f, 0.f, 0.f, 0.f};
    float mr = -3.0e38f, lsum = 0.f;   // per-lane: q-row = w*16 + lr
    unsigned short* Pw = Ps + w * (16 * 64);
    const float C = 0.18033688011112042f;  // 0.125 * log2(e)

    const int nt = SEQ / 64;   // 32
    for (int tt = 0; tt < nt; ++tt) {
        const unsigned short* Kc = Ks[tt & 1];
        const unsigned short* Vc = Vt[tt & 1];

        // swapped QK^T: S^T = K·Q^T -> lane holds q=lr, k=ni*16+lh*4+r
        f32x4 s[4];
#pragma unroll
        for (int ni = 0; ni < 4; ++ni) s[ni] = {0.f, 0.f, 0.f, 0.f};
#pragma unroll
        for (int ks = 0; ks < 2; ++ks) {
#pragma unroll
            for (int ni = 0; ni < 4; ++ni) {
                bf16x8 kb = *(const bf16x8*)(Kc + SWZ(ni * 16 + lr, ks * 4 + lh));
                s[ni] = __builtin_amdgcn_mfma_f32_16x16x32_bf16(kb, qa[ks], s[ni], 0, 0, 0);
            }
        }
        // row max: 15 in-reg + 2 shfl (lanes sharing lr)
        float mx = s[0][0];
#pragma unroll
        for (int ni = 0; ni < 4; ++ni)
#pragma unroll
            for (int r = 0; r < 4; ++r) mx = fmaxf(mx, s[ni][r]);
        mx = fmaxf(mx, __shfl_xor(mx, 16));
        mx = fmaxf(mx, __shfl_xor(mx, 32));
        // defer-max: only rescale when growth beyond e^8 bound (always on tile 0)
        if (__any(mx > mr + 64.0f)) {
            float mn = fmaxf(mr, mx);
            float corr = fexp2((mr - mn) * C);
            mr = mn;
            lsum *= corr;
            float cr[4];
#pragma unroll
            for (int r = 0; r < 4; ++r) cr[r] = __shfl(corr, lh * 4 + r, 16);
#pragma unroll
            for (int nd = 0; nd < 4; ++nd) {
                o[nd][0] *= cr[0]; o[nd][1] *= cr[1];
                o[nd][2] *= cr[2]; o[nd][3] *= cr[3];
            }
        }
        float mc = mr * C;
        float rsum = 0.f;
#pragma unroll
        for (int ni = 0; ni < 4; ++ni)
#pragma unroll
            for (int r = 0; r < 4; ++r) {
                float p = fexp2(fmaf(s[ni][r], C, -mc));
                s[ni][r] = p;
                rsum += p;
            }
        rsum += __shfl_xor(rsum, 16);
        rsum += __shfl_xor(rsum, 32);
        lsum += rsum;
        // P write: packed pairs (adjacent k = r, r+1)
#pragma unroll
        for (int ni = 0; ni < 4; ++ni)
#pragma unroll
            for (int rp = 0; rp < 2; ++rp) {
                int k = ni * 16 + lh * 4 + rp * 2;
                *(unsigned*)(Pw + SWZ(lr, k >> 3) + (k & 7)) =
                    pk2bf(s[ni][rp * 2], s[ni][rp * 2 + 1]);
            }
        // PV: O[q16][d64] += P[q16][k64] @ V[k64][d64]
#pragma unroll
        for (int ks = 0; ks < 2; ++ks) {
            bf16x8 pa = *(const bf16x8*)(Pw + SWZ(lr, ks * 4 + lh));
#pragma unroll
            for (int nd = 0; nd < 4; ++nd) {
                bf16x8 vb = *(const bf16x8*)(Vc + SWZ(nd * 16 + lr, ks * 4 + lh));
                o[nd] = __builtin_amdgcn_mfma_f32_16x16x32_bf16(pa, vb, o[nd], 0, 0, 0);
            }
        }

        // ---- post-compute: write next tile's K/V (regs -> LDS), prefetch t+2 ----
        if (tt + 1 < nt) {
            int nb = (tt & 1) ^ 1;
            // implicit vmcnt wait here covers loads issued one full tile ago
            *(u16x8*)(Ks[nb] + kd0) = k0;
#pragma unroll
            for (int j = 0; j < 4; ++j) {
                int d = vd0 + j;
                unsigned pack = (unsigned)(unsigned short)v0[j] | ((unsigned)(unsigned short)v1[j] << 16);
                *(unsigned*)(Vt[nb] + SWZ(d, vk >> 3) + (vk & 7)) = pack;
            }
            if (tt + 2 < nt) {
                k0 = *(const u16x8*)Kp0;
                v0 = *(const u16x4*)Vp0; v1 = *(const u16x4*)Vp1;
                Kp0 += 64 * 3072; Vp0 += 64 * 3072; Vp1 += 64 * 3072;
            }
            asm volatile("s_waitcnt lgkmcnt(0)" ::: "memory");  // publish nb writes
            __builtin_amdgcn_s_barrier();                        // raw: no vmcnt drain
        }
    }
    // epilogue: redistribute 1/lsum to PV row owners
    float inv = 1.0f / lsum;
    float ir[4];
#pragma unroll
    for (int r = 0; r < 4; ++r) ir[r] = __shfl(inv, lh * 4 + r, 16);
#pragma unroll
    for (int r = 0; r < 4; ++r) {
        int q = q0 + w * 16 + lh * 4 + r;
#pragma unroll
        for (int nd = 0; nd < 4; ++nd) {
            int d = nd * 16 + lr;
            out[(size_t)((size_t)b * SEQ + q) * HDIM + hh * 64 + d] = f2bf(o[nd][r] * ir[r]);
        }
    }
}

extern "C" void kernel_launch(void* const* d_in, const int* in_sizes, int n_in,
                              void* d_out, int out_size, void* d_ws, size_t ws_size,
                              hipStream_t stream)
{
    const float* x     = (const float*)d_in[0];
    const float* ln1_g = (const float*)d_in[1];
    const float* ln1_b = (const float*)d_in[2];
    const float* W_qkv = (const float*)d_in[3];
    const float* b_qkv = (const float*)d_in[4];
    const float* W_out = (const float*)d_in[5];
    const float* b_out = (const float*)d_in[6];
    const float* ln2_g = (const float*)d_in[7];
    const float* ln2_b = (const float*)d_in[8];
    const float* W1    = (const float*)d_in[9];
    const float* b1    = (const float*)d_in[10];
    const float* W2    = (const float*)d_in[11];
    const float* b2    = (const float*)d_in[12];
    float* out = (float*)d_out;
    char* ws8  = (char*)d_ws;

    const int M = BATCH * SEQ;  // 4096
    const size_t MB = 1048576;

    unsigned short* hbuf = (unsigned short*)(ws8);
    unsigned short* qkvb = (unsigned short*)(ws8 + 8 * MB);
    unsigned short* attb = (unsigned short*)(ws8 + 32 * MB);
    unsigned short* ffn1 = (unsigned short*)(ws8 + 8 * MB);
    unsigned short* WqT  = (unsigned short*)(ws8 + 40 * MB);
    unsigned short* WoT  = (unsigned short*)(ws8 + 46 * MB);
    unsigned short* W1T  = (unsigned short*)(ws8 + 48 * MB);
    unsigned short* W2T  = (unsigned short*)(ws8 + 56 * MB);

    // all 4 weight conversions in one launch (12288 blocks)
    wconv_all<<<12288, 256, 0, stream>>>(W_qkv, W_out, W1, W2, WqT, WoT, W1T, W2T);

    ln_kernel<<<M, 256, 0, stream>>>(x, ln1_g, ln1_b, hbuf);
    // QKV: 128x128, grid 24x32 = 768 blocks
    mgemm<0><<<dim3(3 * HDIM / 128, M / 128), 256, 0, stream>>>(hbuf, WqT, b_qkv, nullptr, nullptr, qkvb, M, 3 * HDIM, HDIM);
    mattn<<<dim3(SEQ / 128, NHEAD, BATCH), 512, 0, stream>>>(qkvb, attb);
    // out-proj: 64x128, grid 8x64 = 512 blocks (2/CU), fused residual
    mgemm64<1><<<dim3(HDIM / 128, M / 64), 256, 0, stream>>>(attb, WoT, b_out, x, out, nullptr, M, HDIM, HDIM);
    ln_kernel<<<M, 256, 0, stream>>>(out, ln2_g, ln2_b, hbuf);
    // FFN1: 128x128, grid 32x32 = 1024 blocks, fused gelu
    mgemm<2><<<dim3(4 * HDIM / 128, M / 128), 256, 0, stream>>>(hbuf, W1T, b1, nullptr, nullptr, ffn1, M, 4 * HDIM, HDIM);
    // FFN2: 64x128, grid 8x64 = 512 blocks (2/CU), fused residual (in-place on out)
    mgemm64<1><<<dim3(HDIM / 128, M / 64), 256, 0, stream>>>(ffn1, W2T, b2, out, out, nullptr, M, HDIM, 4 * HDIM);
}

// Round 8
// 220.615 us; speedup vs baseline: 1.3257x; 1.0252x over previous
//
#include <hip/hip_runtime.h>
#include <hip/hip_bf16.h>
#include <math.h>

#define HDIM 1024
#define SEQ  2048
#define BATCH 2
#define NHEAD 16
#define HEADD 64

typedef short bf16x8 __attribute__((ext_vector_type(8)));
typedef float f32x4  __attribute__((ext_vector_type(4)));
typedef unsigned short u16x8 __attribute__((ext_vector_type(8)));
typedef unsigned short u16x4 __attribute__((ext_vector_type(4)));

__device__ __forceinline__ unsigned short f2bf(float f) {
    unsigned u = __float_as_uint(f);
    unsigned r = (u + 0x7FFFu + ((u >> 16) & 1u)) >> 16;
    return (unsigned short)r;
}
__device__ __forceinline__ unsigned pk2bf(float lo, float hi) {
    __hip_bfloat162 h = __float22bfloat162_rn(float2{lo, hi});
    unsigned r;
    __builtin_memcpy(&r, &h, 4);
    return r;
}
__device__ __forceinline__ float fexp2(float x) {
#if __has_builtin(__builtin_amdgcn_exp2f)
    return __builtin_amdgcn_exp2f(x);
#else
    return exp2f(x);
#endif
}
__device__ __forceinline__ float frcp(float x) {
#if __has_builtin(__builtin_amdgcn_rcpf)
    return __builtin_amdgcn_rcpf(x);
#else
    return 1.0f / x;
#endif
}
// Abramowitz-Stegun 7.1.26 erf, |err| < 1.5e-7 (exact at bf16 precision)
__device__ __forceinline__ float erf_fast(float x) {
    float ax = fabsf(x);
    float t = frcp(fmaf(0.3275911f, ax, 1.0f));
    float p = fmaf(t, 1.061405429f, -1.453152027f);
    p = fmaf(p, t, 1.421413741f);
    p = fmaf(p, t, -0.284496736f);
    p = fmaf(p, t, 0.254829592f);
    p *= t;
    float e = fexp2(ax * ax * -1.4426950408889634f);
    return copysignf(fmaf(-p, e, 1.0f), x);
}
__device__ __forceinline__ float gelu_f(float v) {
    return 0.5f * v * (1.0f + erf_fast(v * 0.70710678118654752f));
}
__device__ __forceinline__ void gld16(void* lds, const void* g) {
    __builtin_amdgcn_global_load_lds(
        (const __attribute__((address_space(1))) unsigned int*)(g),
        (__attribute__((address_space(3))) unsigned int*)(lds),
        16, 0, 0);
}

// swizzled element offset for row-major [*][64] bf16 tiles (128B rows, 8 chunks of 16B)
#define SWZ(row, chunk) (((row) * 64) + (((chunk) ^ ((row) & 7)) << 3))

// ---------------- LayerNorm: fp32 in, bf16 out ----------------
__global__ __launch_bounds__(256) void ln_kernel(const float* __restrict__ x,
                                                 const float* __restrict__ gw,
                                                 const float* __restrict__ bw,
                                                 unsigned short* __restrict__ y)
{
    int row = blockIdx.x;
    int t = threadIdx.x;
    const float* xr = x + (size_t)row * HDIM;
    float4 v = *(const float4*)(xr + t * 4);
    float s1 = v.x + v.y + v.z + v.w;
    float s2 = v.x * v.x + v.y * v.y + v.z * v.z + v.w * v.w;
#pragma unroll
    for (int m = 1; m < 64; m <<= 1) {
        s1 += __shfl_xor(s1, m);
        s2 += __shfl_xor(s2, m);
    }
    __shared__ float red[8];
    int wid = t >> 6;
    if ((t & 63) == 0) { red[wid * 2] = s1; red[wid * 2 + 1] = s2; }
    __syncthreads();
    if (t == 0) {
        float a = red[0] + red[2] + red[4] + red[6];
        float b = red[1] + red[3] + red[5] + red[7];
        red[0] = a; red[1] = b;
    }
    __syncthreads();
    float mu  = red[0] * (1.0f / HDIM);
    float var = red[1] * (1.0f / HDIM) - mu * mu;
    float rs  = rsqrtf(var + 1e-5f);
    float4 g4 = *(const float4*)(gw + t * 4);
    float4 b4 = *(const float4*)(bw + t * 4);
    ushort4 o;
    o.x = f2bf((v.x - mu) * rs * g4.x + b4.x);
    o.y = f2bf((v.y - mu) * rs * g4.y + b4.y);
    o.z = f2bf((v.z - mu) * rs * g4.z + b4.z);
    o.w = f2bf((v.w - mu) * rs * g4.w + b4.w);
    *(ushort4*)(y + (size_t)row * HDIM + t * 4) = o;
}

// ------- batched weight fp32 [K][N] -> bf16 transposed [N][K], all 4 weights -------
__global__ __launch_bounds__(256) void wconv_all(const float* __restrict__ Wq,
                                                 const float* __restrict__ Wo,
                                                 const float* __restrict__ W1,
                                                 const float* __restrict__ W2,
                                                 unsigned short* __restrict__ WqT,
                                                 unsigned short* __restrict__ WoT,
                                                 unsigned short* __restrict__ W1T,
                                                 unsigned short* __restrict__ W2T)
{
    int bid = blockIdx.x;
    const float* W; unsigned short* WT; int K, nx, idx;
    if (bid < 3072)      { W = Wq; WT = WqT; K = 1024; nx = 96;  idx = bid; }
    else if (bid < 4096) { W = Wo; WT = WoT; K = 1024; nx = 32;  idx = bid - 3072; }
    else if (bid < 8192) { W = W1; WT = W1T; K = 1024; nx = 128; idx = bid - 4096; }
    else                 { W = W2; WT = W2T; K = 4096; nx = 32;  idx = bid - 8192; }
    int N = nx * 32;
    int n0 = (idx % nx) * 32, k0 = (idx / nx) * 32;

    __shared__ float tile[32][33];
    int t = threadIdx.x, c = t & 31, r = t >> 5;
#pragma unroll
    for (int i = 0; i < 4; ++i)
        tile[r + 8 * i][c] = W[(size_t)(k0 + r + 8 * i) * N + n0 + c];
    __syncthreads();
#pragma unroll
    for (int i = 0; i < 4; ++i)
        WT[(size_t)(n0 + r + 8 * i) * K + k0 + c] = f2bf(tile[c][r + 8 * i]);
}

// ------------- MFMA GEMM 128x128: BK=64, dbuf LDS 64KB, 1 barrier/K-tile -------------
// Round-1 verified structure (0 bank conflicts), default block mapping (the HW
// round-robin already gives each XCD a fixed bx residue class = good B locality;
// round-7's remap proved this by regressing FETCH 41->70MB).
// NEW: B-column interleave -- LDS B row (wn*64 + ni*16 + lr) holds BT global row
// (bn + wn*64 + lr*4 + ni), so each lane's 4 ni-accumulators are 4 CONTIGUOUS
// output columns -> epilogue is 16 vector stores (ushort4/float4) not 64 scalar.
template <int EPI>
__global__ __launch_bounds__(256, 2) void mgemm(const unsigned short* __restrict__ A,
                                                const unsigned short* __restrict__ BT,
                                                const float* __restrict__ bias,
                                                const float* __restrict__ resid,
                                                float* __restrict__ Cf,
                                                unsigned short* __restrict__ Cb,
                                                int M, int N, int K)
{
    __shared__ char smem[65536];   // [2 bufs][A 16KB | B 16KB]
    int t = threadIdx.x;
    int bn = blockIdx.x * 128, bm = blockIdx.y * 128;
    int l = t & 63, w = t >> 6;
    int wm = w >> 1, wn = w & 1;
    int lrow = l & 15, kq = l >> 4;

    f32x4 acc[4][4];
#pragma unroll
    for (int i = 0; i < 4; ++i)
#pragma unroll
        for (int j = 0; j < 4; ++j) acc[i][j] = {0.f, 0.f, 0.f, 0.f};

    const unsigned short* Ap[4];
    const unsigned short* Bp[4];
    int ld[4];
#pragma unroll
    for (int i = 0; i < 4; ++i) {
        int cid = i * 256 + t;
        int row = cid >> 3, c = cid & 7;
        int gc = (c ^ (row & 7)) << 3;
        Ap[i] = A + (size_t)(bm + row) * K + gc;
        // B-column interleave: LDS row -> permuted BT row (see header comment)
        int prow = (row & 64) + ((row & 15) << 2) + ((row >> 4) & 3);
        Bp[i] = BT + (size_t)(bn + prow) * K + gc;
        ld[i] = cid << 4;
    }

    int nt = K >> 6;
#pragma unroll
    for (int i = 0; i < 4; ++i) {
        gld16(smem + ld[i], Ap[i]);
        gld16(smem + 16384 + ld[i], Bp[i]);
    }
    __syncthreads();

    for (int tk = 0; tk < nt; ++tk) {
        int cur = (tk & 1) << 15;
        if (tk + 1 < nt) {
            int k0 = (tk + 1) << 6;
            int nxt = 32768 - cur;
#pragma unroll
            for (int i = 0; i < 4; ++i) {
                gld16(smem + nxt + ld[i], Ap[i] + k0);
                gld16(smem + nxt + 16384 + ld[i], Bp[i] + k0);
            }
        }
        const unsigned short* sA = (const unsigned short*)(smem + cur);
        const unsigned short* sB = (const unsigned short*)(smem + cur + 16384);
#pragma unroll
        for (int kk = 0; kk < 2; ++kk) {
            bf16x8 af[4], bv[4];
#pragma unroll
            for (int mi = 0; mi < 4; ++mi)
                af[mi] = *(const bf16x8*)(sA + SWZ(wm * 64 + mi * 16 + lrow, kk * 4 + kq));
#pragma unroll
            for (int ni = 0; ni < 4; ++ni)
                bv[ni] = *(const bf16x8*)(sB + SWZ(wn * 64 + ni * 16 + lrow, kk * 4 + kq));
#pragma unroll
            for (int mi = 0; mi < 4; ++mi)
#pragma unroll
                for (int ni = 0; ni < 4; ++ni)
                    acc[mi][ni] = __builtin_amdgcn_mfma_f32_16x16x32_bf16(af[mi], bv[ni], acc[mi][ni], 0, 0, 0);
        }
        __syncthreads();
    }

    int crow = (l >> 4) * 4;
    int ccol = l & 15;
    int gcolb = bn + wn * 64 + ccol * 4;   // 4 contiguous output columns
    float4 b4 = *(const float4*)(bias + gcolb);
#pragma unroll
    for (int mi = 0; mi < 4; ++mi) {
#pragma unroll
        for (int r = 0; r < 4; ++r) {
            int grow = bm + wm * 64 + mi * 16 + crow + r;
            size_t off = (size_t)grow * N + gcolb;
            float v0 = acc[mi][0][r] + b4.x;
            float v1 = acc[mi][1][r] + b4.y;
            float v2 = acc[mi][2][r] + b4.z;
            float v3 = acc[mi][3][r] + b4.w;
            if (EPI == 1) {
                float4 rr = *(const float4*)(resid + off);
                float4 o4 = {v0 + rr.x, v1 + rr.y, v2 + rr.z, v3 + rr.w};
                *(float4*)(Cf + off) = o4;
            } else {
                if (EPI == 2) {
                    v0 = gelu_f(v0); v1 = gelu_f(v1); v2 = gelu_f(v2); v3 = gelu_f(v3);
                }
                ushort4 o4 = {f2bf(v0), f2bf(v1), f2bf(v2), f2bf(v3)};
                *(ushort4*)(Cb + off) = o4;
            }
        }
    }
}

// ------------- MFMA GEMM 64x128: geometry-halved variant for N=1024 shapes -------------
// grid (8, M/64) = 512 blocks -> 2 blocks/CU.  LDS = 2 x (A 8KB + B 16KB) = 48KB.
// Same sync edges / swizzle / staging idiom.  B-column interleave (2-wide).
template <int EPI>
__global__ __launch_bounds__(256, 2) void mgemm64(const unsigned short* __restrict__ A,
                                                  const unsigned short* __restrict__ BT,
                                                  const float* __restrict__ bias,
                                                  const float* __restrict__ resid,
                                                  float* __restrict__ Cf,
                                                  unsigned short* __restrict__ Cb,
                                                  int M, int N, int K)
{
    __shared__ char smem[49152];   // [2 bufs][A 8KB | B 16KB]
    int t = threadIdx.x;
    int bn = blockIdx.x * 128, bm = blockIdx.y * 64;
    int l = t & 63, w = t >> 6;       // 4 waves: 1M x 4N; per-wave C = 64x32
    int lrow = l & 15, kq = l >> 4;

    f32x4 acc[4][2];
#pragma unroll
    for (int i = 0; i < 4; ++i)
#pragma unroll
        for (int j = 0; j < 2; ++j) acc[i][j] = {0.f, 0.f, 0.f, 0.f};

    const unsigned short* Ap[2];
    int ldA[2];
#pragma unroll
    for (int i = 0; i < 2; ++i) {
        int cid = i * 256 + t;
        int row = cid >> 3, c = cid & 7;
        Ap[i] = A + (size_t)(bm + row) * K + ((c ^ (row & 7)) << 3);
        ldA[i] = cid << 4;
    }
    const unsigned short* Bp[4];
    int ldB[4];
#pragma unroll
    for (int i = 0; i < 4; ++i) {
        int cid = i * 256 + t;
        int row = cid >> 3, c = cid & 7;
        // 2-wide column interleave: LDS row (w*32 + ni*16 + lr) <- BT row (w*32 + lr*2 + ni)
        int prow = (row & ~31) + ((row & 15) << 1) + ((row >> 4) & 1);
        Bp[i] = BT + (size_t)(bn + prow) * K + ((c ^ (row & 7)) << 3);
        ldB[i] = cid << 4;
    }

    int nt = K >> 6;
#pragma unroll
    for (int i = 0; i < 2; ++i) gld16(smem + ldA[i], Ap[i]);
#pragma unroll
    for (int i = 0; i < 4; ++i) gld16(smem + 8192 + ldB[i], Bp[i]);
    __syncthreads();

    for (int tk = 0; tk < nt; ++tk) {
        int cur = (tk & 1) * 24576;
        if (tk + 1 < nt) {
            int k0 = (tk + 1) << 6;
            int nxt = 24576 - cur;
#pragma unroll
            for (int i = 0; i < 2; ++i) gld16(smem + nxt + ldA[i], Ap[i] + k0);
#pragma unroll
            for (int i = 0; i < 4; ++i) gld16(smem + nxt + 8192 + ldB[i], Bp[i] + k0);
        }
        const unsigned short* sA = (const unsigned short*)(smem + cur);
        const unsigned short* sB = (const unsigned short*)(smem + cur + 8192);
#pragma unroll
        for (int kk = 0; kk < 2; ++kk) {
            bf16x8 af[4], bv[2];
#pragma unroll
            for (int mi = 0; mi < 4; ++mi)
                af[mi] = *(const bf16x8*)(sA + SWZ(mi * 16 + lrow, kk * 4 + kq));
#pragma unroll
            for (int ni = 0; ni < 2; ++ni)
                bv[ni] = *(const bf16x8*)(sB + SWZ(w * 32 + ni * 16 + lrow, kk * 4 + kq));
#pragma unroll
            for (int mi = 0; mi < 4; ++mi)
#pragma unroll
                for (int ni = 0; ni < 2; ++ni)
                    acc[mi][ni] = __builtin_amdgcn_mfma_f32_16x16x32_bf16(af[mi], bv[ni], acc[mi][ni], 0, 0, 0);
        }
        __syncthreads();
    }

    int crow = (l >> 4) * 4;
    int ccol = l & 15;
    int gcolb = bn + w * 32 + ccol * 2;   // 2 contiguous output columns
    float2 b2 = *(const float2*)(bias + gcolb);
#pragma unroll
    for (int mi = 0; mi < 4; ++mi) {
#pragma unroll
        for (int r = 0; r < 4; ++r) {
            int grow = bm + mi * 16 + crow + r;
            size_t off = (size_t)grow * N + gcolb;
            float v0 = acc[mi][0][r] + b2.x;
            float v1 = acc[mi][1][r] + b2.y;
            if (EPI == 1) {
                float2 rr = *(const float2*)(resid + off);
                float2 o2 = {v0 + rr.x, v1 + rr.y};
                *(float2*)(Cf + off) = o2;
            } else {
                if (EPI == 2) { v0 = gelu_f(v0); v1 = gelu_f(v1); }
                *(unsigned*)(Cb + off) = pk2bf(v0, v1);
            }
        }
    }
}

// ---------------- MFMA flash attention v3: 128 q-rows / 8 waves per block ----------------
__global__ __launch_bounds__(512) void mattn(const unsigned short* __restrict__ qkv,
                                             unsigned short* __restrict__ out)
{
    __shared__ unsigned short Qs[128 * 64];       // [q][d] swizzled (16KB)
    __shared__ unsigned short Ks[2][64 * 64];     // [k][d] swizzled, dbuf (16KB)
    __shared__ unsigned short Vt[2][64 * 64];     // [d][k] swizzled, dbuf (16KB)
    __shared__ unsigned short Ps[8 * 16 * 64];    // per-wave [q16][k64] swizzled (16KB)
    int t = threadIdx.x;
    int w = t >> 6, l = t & 63;
    int lr = l & 15, lh = l >> 4;
    int q0 = blockIdx.x * 128;
    int hh = blockIdx.y, b = blockIdx.z;
    const unsigned short* Qg = qkv + (size_t)b * SEQ * 3072 + hh * 64;
    const unsigned short* Kg = Qg + 1024;
    const unsigned short* Vg = Qg + 2048;

    // ---- stage Q via gld16 (pre-swizzled global source): 1024 chunks, 2/thread ----
#pragma unroll
    for (int i = 0; i < 2; ++i) {
        int chunkid = i * 512 + t;
        int row = chunkid >> 3, c = chunkid & 7;
        gld16(((char*)Qs) + chunkid * 16,
              Qg + (size_t)(q0 + row) * 3072 + ((c ^ (row & 7)) << 3));
    }

    // ---- K reg-staging: 512 chunks (64 rows x 8), 1 per thread ----
    int kr0 = t >> 3, kc0 = t & 7;
    const unsigned short* Kp0 = Kg + (size_t)kr0 * 3072 + kc0 * 8;
    int kd0 = SWZ(kr0, kc0);
    // ---- V: thread handles k-pair (vk,vk+1) x 4 d-elems ----
    int vk = (t & 31) * 2;
    int vd0 = ((t >> 5) & 15) * 4;
    const unsigned short* Vp0 = Vg + (size_t)vk * 3072 + vd0;
    const unsigned short* Vp1 = Vp0 + 3072;

    // prologue: load K/V tile 0 to regs
    u16x8 k0 = *(const u16x8*)Kp0;
    u16x4 v0 = *(const u16x4*)Vp0;
    u16x4 v1 = *(const u16x4*)Vp1;
    Kp0 += 64 * 3072; Vp0 += 64 * 3072; Vp1 += 64 * 3072;

    __syncthreads();   // Qs ready (full drain; prologue only)
    bf16x8 qa[2];
#pragma unroll
    for (int ks = 0; ks < 2; ++ks)
        qa[ks] = *(const bf16x8*)(Qs + SWZ(w * 16 + lr, ks * 4 + lh));

    // write tile 0 into buffer 0
    *(u16x8*)(Ks[0] + kd0) = k0;
#pragma unroll
    for (int j = 0; j < 4; ++j) {
        int d = vd0 + j;
        unsigned pack = (unsigned)(unsigned short)v0[j] | ((unsigned)(unsigned short)v1[j] << 16);
        *(unsigned*)(Vt[0] + SWZ(d, vk >> 3) + (vk & 7)) = pack;
    }
    // prefetch tile 1 to regs (stays in flight across the raw barrier)
    k0 = *(const u16x8*)Kp0;
    v0 = *(const u16x4*)Vp0; v1 = *(const u16x4*)Vp1;
    Kp0 += 64 * 3072; Vp0 += 64 * 3072; Vp1 += 64 * 3072;
    asm volatile("s_waitcnt lgkmcnt(0)" ::: "memory");   // publish buf0 writes
    __builtin_amdgcn_s_barrier();

    f32x4 o[4];
#pragma unroll
    for (int i = 0; i < 4; ++i) o[i] = {0.f, 0.f, 0.f, 0.f};
    float mr = -3.0e38f, lsum = 0.f;   // per-lane: q-row = w*16 + lr
    unsigned short* Pw = Ps + w * (16 * 64);
    const float C = 0.18033688011112042f;  // 0.125 * log2(e)

    const int nt = SEQ / 64;   // 32
    for (int tt = 0; tt < nt; ++tt) {
        const unsigned short* Kc = Ks[tt & 1];
        const unsigned short* Vc = Vt[tt & 1];

        // swapped QK^T: S^T = K·Q^T -> lane holds q=lr, k=ni*16+lh*4+r
        f32x4 s[4];
#pragma unroll
        for (int ni = 0; ni < 4; ++ni) s[ni] = {0.f, 0.f, 0.f, 0.f};
#pragma unroll
        for (int ks = 0; ks < 2; ++ks) {
#pragma unroll
            for (int ni = 0; ni < 4; ++ni) {
                bf16x8 kb = *(const bf16x8*)(Kc + SWZ(ni * 16 + lr, ks * 4 + lh));
                s[ni] = __builtin_amdgcn_mfma_f32_16x16x32_bf16(kb, qa[ks], s[ni], 0, 0, 0);
            }
        }
        // row max: 15 in-reg + 2 shfl (lanes sharing lr)
        float mx = s[0][0];
#pragma unroll
        for (int ni = 0; ni < 4; ++ni)
#pragma unroll
            for (int r = 0; r < 4; ++r) mx = fmaxf(mx, s[ni][r]);
        mx = fmaxf(mx, __shfl_xor(mx, 16));
        mx = fmaxf(mx, __shfl_xor(mx, 32));
        // defer-max: only rescale when growth beyond e^8 bound (always on tile 0)
        if (__any(mx > mr + 64.0f)) {
            float mn = fmaxf(mr, mx);
            float corr = fexp2((mr - mn) * C);
            mr = mn;
            lsum *= corr;
            float cr[4];
#pragma unroll
            for (int r = 0; r < 4; ++r) cr[r] = __shfl(corr, lh * 4 + r, 16);
#pragma unroll
            for (int nd = 0; nd < 4; ++nd) {
                o[nd][0] *= cr[0]; o[nd][1] *= cr[1];
                o[nd][2] *= cr[2]; o[nd][3] *= cr[3];
            }
        }
        float mc = mr * C;
        float rsum = 0.f;
#pragma unroll
        for (int ni = 0; ni < 4; ++ni)
#pragma unroll
            for (int r = 0; r < 4; ++r) {
                float p = fexp2(fmaf(s[ni][r], C, -mc));
                s[ni][r] = p;
                rsum += p;
            }
        rsum += __shfl_xor(rsum, 16);
        rsum += __shfl_xor(rsum, 32);
        lsum += rsum;
        // P write: packed pairs (adjacent k = r, r+1)
#pragma unroll
        for (int ni = 0; ni < 4; ++ni)
#pragma unroll
            for (int rp = 0; rp < 2; ++rp) {
                int k = ni * 16 + lh * 4 + rp * 2;
                *(unsigned*)(Pw + SWZ(lr, k >> 3) + (k & 7)) =
                    pk2bf(s[ni][rp * 2], s[ni][rp * 2 + 1]);
            }
        // PV: O[q16][d64] += P[q16][k64] @ V[k64][d64]
#pragma unroll
        for (int ks = 0; ks < 2; ++ks) {
            bf16x8 pa = *(const bf16x8*)(Pw + SWZ(lr, ks * 4 + lh));
#pragma unroll
            for (int nd = 0; nd < 4; ++nd) {
                bf16x8 vb = *(const bf16x8*)(Vc + SWZ(nd * 16 + lr, ks * 4 + lh));
                o[nd] = __builtin_amdgcn_mfma_f32_16x16x32_bf16(pa, vb, o[nd], 0, 0, 0);
            }
        }

        // ---- post-compute: write next tile's K/V (regs -> LDS), prefetch t+2 ----
        if (tt + 1 < nt) {
            int nb = (tt & 1) ^ 1;
            // implicit vmcnt wait here covers loads issued one full tile ago
            *(u16x8*)(Ks[nb] + kd0) = k0;
#pragma unroll
            for (int j = 0; j < 4; ++j) {
                int d = vd0 + j;
                unsigned pack = (unsigned)(unsigned short)v0[j] | ((unsigned)(unsigned short)v1[j] << 16);
                *(unsigned*)(Vt[nb] + SWZ(d, vk >> 3) + (vk & 7)) = pack;
            }
            if (tt + 2 < nt) {
                k0 = *(const u16x8*)Kp0;
                v0 = *(const u16x4*)Vp0; v1 = *(const u16x4*)Vp1;
                Kp0 += 64 * 3072; Vp0 += 64 * 3072; Vp1 += 64 * 3072;
            }
            asm volatile("s_waitcnt lgkmcnt(0)" ::: "memory");  // publish nb writes
            __builtin_amdgcn_s_barrier();                        // raw: no vmcnt drain
        }
    }
    // epilogue: redistribute 1/lsum to PV row owners
    float inv = 1.0f / lsum;
    float ir[4];
#pragma unroll
    for (int r = 0; r < 4; ++r) ir[r] = __shfl(inv, lh * 4 + r, 16);
#pragma unroll
    for (int r = 0; r < 4; ++r) {
        int q = q0 + w * 16 + lh * 4 + r;
#pragma unroll
        for (int nd = 0; nd < 4; ++nd) {
            int d = nd * 16 + lr;
            out[(size_t)((size_t)b * SEQ + q) * HDIM + hh * 64 + d] = f2bf(o[nd][r] * ir[r]);
        }
    }
}

extern "C" void kernel_launch(void* const* d_in, const int* in_sizes, int n_in,
                              void* d_out, int out_size, void* d_ws, size_t ws_size,
                              hipStream_t stream)
{
    const float* x     = (const float*)d_in[0];
    const float* ln1_g = (const float*)d_in[1];
    const float* ln1_b = (const float*)d_in[2];
    const float* W_qkv = (const float*)d_in[3];
    const float* b_qkv = (const float*)d_in[4];
    const float* W_out = (const float*)d_in[5];
    const float* b_out = (const float*)d_in[6];
    const float* ln2_g = (const float*)d_in[7];
    const float* ln2_b = (const float*)d_in[8];
    const float* W1    = (const float*)d_in[9];
    const float* b1    = (const float*)d_in[10];
    const float* W2    = (const float*)d_in[11];
    const float* b2    = (const float*)d_in[12];
    float* out = (float*)d_out;
    char* ws8  = (char*)d_ws;

    const int M = BATCH * SEQ;  // 4096
    const size_t MB = 1048576;

    unsigned short* hbuf = (unsigned short*)(ws8);
    unsigned short* qkvb = (unsigned short*)(ws8 + 8 * MB);
    unsigned short* attb = (unsigned short*)(ws8 + 32 * MB);
    unsigned short* ffn1 = (unsigned short*)(ws8 + 8 * MB);
    unsigned short* WqT  = (unsigned short*)(ws8 + 40 * MB);
    unsigned short* WoT  = (unsigned short*)(ws8 + 46 * MB);
    unsigned short* W1T  = (unsigned short*)(ws8 + 48 * MB);
    unsigned short* W2T  = (unsigned short*)(ws8 + 56 * MB);

    // all 4 weight conversions in one launch (12288 blocks)
    wconv_all<<<12288, 256, 0, stream>>>(W_qkv, W_out, W1, W2, WqT, WoT, W1T, W2T);

    ln_kernel<<<M, 256, 0, stream>>>(x, ln1_g, ln1_b, hbuf);
    // QKV: 128x128, grid 24x32 = 768 blocks
    mgemm<0><<<dim3(3 * HDIM / 128, M / 128), 256, 0, stream>>>(hbuf, WqT, b_qkv, nullptr, nullptr, qkvb, M, 3 * HDIM, HDIM);
    mattn<<<dim3(SEQ / 128, NHEAD, BATCH), 512, 0, stream>>>(qkvb, attb);
    // out-proj: 64x128, grid 8x64 = 512 blocks (2/CU), fused residual
    mgemm64<1><<<dim3(HDIM / 128, M / 64), 256, 0, stream>>>(attb, WoT, b_out, x, out, nullptr, M, HDIM, HDIM);
    ln_kernel<<<M, 256, 0, stream>>>(out, ln2_g, ln2_b, hbuf);
    // FFN1: 128x128, grid 32x32 = 1024 blocks, fused gelu
    mgemm<2><<<dim3(4 * HDIM / 128, M / 128), 256, 0, stream>>>(hbuf, W1T, b1, nullptr, nullptr, ffn1, M, 4 * HDIM, HDIM);
    // FFN2: 64x128, grid 8x64 = 512 blocks (2/CU), fused residual (in-place on out)
    mgemm64<1><<<dim3(HDIM / 128, M / 64), 256, 0, stream>>>(ffn1, W2T, b2, out, out, nullptr, M, HDIM, 4 * HDIM);
}

// Round 9
// 217.304 us; speedup vs baseline: 1.3459x; 1.0152x over previous
//
#include <hip/hip_runtime.h>
#include <hip/hip_bf16.h>
#include <math.h>

#define HDIM 1024
#define SEQ  2048
#define BATCH 2
#define NHEAD 16
#define HEADD 64

typedef short bf16x8 __attribute__((ext_vector_type(8)));
typedef float f32x4  __attribute__((ext_vector_type(4)));
typedef unsigned short u16x8 __attribute__((ext_vector_type(8)));
typedef unsigned short u16x4 __attribute__((ext_vector_type(4)));

__device__ __forceinline__ unsigned short f2bf(float f) {
    unsigned u = __float_as_uint(f);
    unsigned r = (u + 0x7FFFu + ((u >> 16) & 1u)) >> 16;
    return (unsigned short)r;
}
__device__ __forceinline__ unsigned pk2bf(float lo, float hi) {
    __hip_bfloat162 h = __float22bfloat162_rn(float2{lo, hi});
    unsigned r;
    __builtin_memcpy(&r, &h, 4);
    return r;
}
__device__ __forceinline__ float fexp2(float x) {
#if __has_builtin(__builtin_amdgcn_exp2f)
    return __builtin_amdgcn_exp2f(x);
#else
    return exp2f(x);
#endif
}
__device__ __forceinline__ float frcp(float x) {
#if __has_builtin(__builtin_amdgcn_rcpf)
    return __builtin_amdgcn_rcpf(x);
#else
    return 1.0f / x;
#endif
}
// Abramowitz-Stegun 7.1.26 erf, |err| < 1.5e-7 (exact at bf16 precision)
__device__ __forceinline__ float erf_fast(float x) {
    float ax = fabsf(x);
    float t = frcp(fmaf(0.3275911f, ax, 1.0f));
    float p = fmaf(t, 1.061405429f, -1.453152027f);
    p = fmaf(p, t, 1.421413741f);
    p = fmaf(p, t, -0.284496736f);
    p = fmaf(p, t, 0.254829592f);
    p *= t;
    float e = fexp2(ax * ax * -1.4426950408889634f);
    return copysignf(fmaf(-p, e, 1.0f), x);
}
__device__ __forceinline__ float gelu_f(float v) {
    return 0.5f * v * (1.0f + erf_fast(v * 0.70710678118654752f));
}
__device__ __forceinline__ void gld16(void* lds, const void* g) {
    __builtin_amdgcn_global_load_lds(
        (const __attribute__((address_space(1))) unsigned int*)(g),
        (__attribute__((address_space(3))) unsigned int*)(lds),
        16, 0, 0);
}

// swizzled element offset for row-major [*][64] bf16 tiles (128B rows, 8 chunks of 16B)
#define SWZ(row, chunk) (((row) * 64) + (((chunk) ^ ((row) & 7)) << 3))

// ---------------- LayerNorm: fp32 in, bf16 out ----------------
__global__ __launch_bounds__(256) void ln_kernel(const float* __restrict__ x,
                                                 const float* __restrict__ gw,
                                                 const float* __restrict__ bw,
                                                 unsigned short* __restrict__ y)
{
    int row = blockIdx.x;
    int t = threadIdx.x;
    const float* xr = x + (size_t)row * HDIM;
    float4 v = *(const float4*)(xr + t * 4);
    float s1 = v.x + v.y + v.z + v.w;
    float s2 = v.x * v.x + v.y * v.y + v.z * v.z + v.w * v.w;
#pragma unroll
    for (int m = 1; m < 64; m <<= 1) {
        s1 += __shfl_xor(s1, m);
        s2 += __shfl_xor(s2, m);
    }
    __shared__ float red[8];
    int wid = t >> 6;
    if ((t & 63) == 0) { red[wid * 2] = s1; red[wid * 2 + 1] = s2; }
    __syncthreads();
    if (t == 0) {
        float a = red[0] + red[2] + red[4] + red[6];
        float b = red[1] + red[3] + red[5] + red[7];
        red[0] = a; red[1] = b;
    }
    __syncthreads();
    float mu  = red[0] * (1.0f / HDIM);
    float var = red[1] * (1.0f / HDIM) - mu * mu;
    float rs  = rsqrtf(var + 1e-5f);
    float4 g4 = *(const float4*)(gw + t * 4);
    float4 b4 = *(const float4*)(bw + t * 4);
    ushort4 o;
    o.x = f2bf((v.x - mu) * rs * g4.x + b4.x);
    o.y = f2bf((v.y - mu) * rs * g4.y + b4.y);
    o.z = f2bf((v.z - mu) * rs * g4.z + b4.z);
    o.w = f2bf((v.w - mu) * rs * g4.w + b4.w);
    *(ushort4*)(y + (size_t)row * HDIM + t * 4) = o;
}

// ------- batched weight fp32 [K][N] -> bf16 transposed [N][K], all 4 weights -------
__global__ __launch_bounds__(256) void wconv_all(const float* __restrict__ Wq,
                                                 const float* __restrict__ Wo,
                                                 const float* __restrict__ W1,
                                                 const float* __restrict__ W2,
                                                 unsigned short* __restrict__ WqT,
                                                 unsigned short* __restrict__ WoT,
                                                 unsigned short* __restrict__ W1T,
                                                 unsigned short* __restrict__ W2T)
{
    int bid = blockIdx.x;
    const float* W; unsigned short* WT; int K, nx, idx;
    if (bid < 3072)      { W = Wq; WT = WqT; K = 1024; nx = 96;  idx = bid; }
    else if (bid < 4096) { W = Wo; WT = WoT; K = 1024; nx = 32;  idx = bid - 3072; }
    else if (bid < 8192) { W = W1; WT = W1T; K = 1024; nx = 128; idx = bid - 4096; }
    else                 { W = W2; WT = W2T; K = 4096; nx = 32;  idx = bid - 8192; }
    int N = nx * 32;
    int n0 = (idx % nx) * 32, k0 = (idx / nx) * 32;

    __shared__ float tile[32][33];
    int t = threadIdx.x, c = t & 31, r = t >> 5;
#pragma unroll
    for (int i = 0; i < 4; ++i)
        tile[r + 8 * i][c] = W[(size_t)(k0 + r + 8 * i) * N + n0 + c];
    __syncthreads();
#pragma unroll
    for (int i = 0; i < 4; ++i)
        WT[(size_t)(n0 + r + 8 * i) * K + k0 + c] = f2bf(tile[c][r + 8 * i]);
}

// ------------- MFMA GEMM 128x128: BK=64, dbuf LDS 64KB, 1 barrier/K-tile -------------
// Round-1 verified structure (0 bank conflicts), default block mapping.
// B-column interleave: lane's 4 ni-accumulators = 4 contiguous output columns
// -> vector epilogue (16 x ushort4/float4 stores).
template <int EPI>
__global__ __launch_bounds__(256, 2) void mgemm(const unsigned short* __restrict__ A,
                                                const unsigned short* __restrict__ BT,
                                                const float* __restrict__ bias,
                                                const float* __restrict__ resid,
                                                float* __restrict__ Cf,
                                                unsigned short* __restrict__ Cb,
                                                int M, int N, int K)
{
    __shared__ char smem[65536];   // [2 bufs][A 16KB | B 16KB]
    int t = threadIdx.x;
    int bn = blockIdx.x * 128, bm = blockIdx.y * 128;
    int l = t & 63, w = t >> 6;
    int wm = w >> 1, wn = w & 1;
    int lrow = l & 15, kq = l >> 4;

    f32x4 acc[4][4];
#pragma unroll
    for (int i = 0; i < 4; ++i)
#pragma unroll
        for (int j = 0; j < 4; ++j) acc[i][j] = {0.f, 0.f, 0.f, 0.f};

    const unsigned short* Ap[4];
    const unsigned short* Bp[4];
    int ld[4];
#pragma unroll
    for (int i = 0; i < 4; ++i) {
        int cid = i * 256 + t;
        int row = cid >> 3, c = cid & 7;
        int gc = (c ^ (row & 7)) << 3;
        Ap[i] = A + (size_t)(bm + row) * K + gc;
        // B-column interleave: LDS row -> permuted BT row
        int prow = (row & 64) + ((row & 15) << 2) + ((row >> 4) & 3);
        Bp[i] = BT + (size_t)(bn + prow) * K + gc;
        ld[i] = cid << 4;
    }

    int nt = K >> 6;
#pragma unroll
    for (int i = 0; i < 4; ++i) {
        gld16(smem + ld[i], Ap[i]);
        gld16(smem + 16384 + ld[i], Bp[i]);
    }
    __syncthreads();

    for (int tk = 0; tk < nt; ++tk) {
        int cur = (tk & 1) << 15;
        if (tk + 1 < nt) {
            int k0 = (tk + 1) << 6;
            int nxt = 32768 - cur;
#pragma unroll
            for (int i = 0; i < 4; ++i) {
                gld16(smem + nxt + ld[i], Ap[i] + k0);
                gld16(smem + nxt + 16384 + ld[i], Bp[i] + k0);
            }
        }
        const unsigned short* sA = (const unsigned short*)(smem + cur);
        const unsigned short* sB = (const unsigned short*)(smem + cur + 16384);
#pragma unroll
        for (int kk = 0; kk < 2; ++kk) {
            bf16x8 af[4], bv[4];
#pragma unroll
            for (int mi = 0; mi < 4; ++mi)
                af[mi] = *(const bf16x8*)(sA + SWZ(wm * 64 + mi * 16 + lrow, kk * 4 + kq));
#pragma unroll
            for (int ni = 0; ni < 4; ++ni)
                bv[ni] = *(const bf16x8*)(sB + SWZ(wn * 64 + ni * 16 + lrow, kk * 4 + kq));
#pragma unroll
            for (int mi = 0; mi < 4; ++mi)
#pragma unroll
                for (int ni = 0; ni < 4; ++ni)
                    acc[mi][ni] = __builtin_amdgcn_mfma_f32_16x16x32_bf16(af[mi], bv[ni], acc[mi][ni], 0, 0, 0);
        }
        __syncthreads();
    }

    int crow = (l >> 4) * 4;
    int ccol = l & 15;
    int gcolb = bn + wn * 64 + ccol * 4;   // 4 contiguous output columns
    float4 b4 = *(const float4*)(bias + gcolb);
#pragma unroll
    for (int mi = 0; mi < 4; ++mi) {
#pragma unroll
        for (int r = 0; r < 4; ++r) {
            int grow = bm + wm * 64 + mi * 16 + crow + r;
            size_t off = (size_t)grow * N + gcolb;
            float v0 = acc[mi][0][r] + b4.x;
            float v1 = acc[mi][1][r] + b4.y;
            float v2 = acc[mi][2][r] + b4.z;
            float v3 = acc[mi][3][r] + b4.w;
            if (EPI == 1) {
                float4 rr = *(const float4*)(resid + off);
                float4 o4 = {v0 + rr.x, v1 + rr.y, v2 + rr.z, v3 + rr.w};
                *(float4*)(Cf + off) = o4;
            } else {
                if (EPI == 2) {
                    v0 = gelu_f(v0); v1 = gelu_f(v1); v2 = gelu_f(v2); v3 = gelu_f(v3);
                }
                ushort4 o4 = {f2bf(v0), f2bf(v1), f2bf(v2), f2bf(v3)};
                *(ushort4*)(Cb + off) = o4;
            }
        }
    }
}

// ------------- MFMA GEMM 64x128: geometry-halved variant for N=1024 shapes -------------
// grid (8, M/64) = 512 blocks -> 2 blocks/CU.  LDS = 2 x (A 8KB + B 16KB) = 48KB.
template <int EPI>
__global__ __launch_bounds__(256, 2) void mgemm64(const unsigned short* __restrict__ A,
                                                  const unsigned short* __restrict__ BT,
                                                  const float* __restrict__ bias,
                                                  const float* __restrict__ resid,
                                                  float* __restrict__ Cf,
                                                  unsigned short* __restrict__ Cb,
                                                  int M, int N, int K)
{
    __shared__ char smem[49152];   // [2 bufs][A 8KB | B 16KB]
    int t = threadIdx.x;
    int bn = blockIdx.x * 128, bm = blockIdx.y * 64;
    int l = t & 63, w = t >> 6;       // 4 waves: 1M x 4N; per-wave C = 64x32
    int lrow = l & 15, kq = l >> 4;

    f32x4 acc[4][2];
#pragma unroll
    for (int i = 0; i < 4; ++i)
#pragma unroll
        for (int j = 0; j < 2; ++j) acc[i][j] = {0.f, 0.f, 0.f, 0.f};

    const unsigned short* Ap[2];
    int ldA[2];
#pragma unroll
    for (int i = 0; i < 2; ++i) {
        int cid = i * 256 + t;
        int row = cid >> 3, c = cid & 7;
        Ap[i] = A + (size_t)(bm + row) * K + ((c ^ (row & 7)) << 3);
        ldA[i] = cid << 4;
    }
    const unsigned short* Bp[4];
    int ldB[4];
#pragma unroll
    for (int i = 0; i < 4; ++i) {
        int cid = i * 256 + t;
        int row = cid >> 3, c = cid & 7;
        // 2-wide column interleave: LDS row (w*32 + ni*16 + lr) <- BT row (w*32 + lr*2 + ni)
        int prow = (row & ~31) + ((row & 15) << 1) + ((row >> 4) & 1);
        Bp[i] = BT + (size_t)(bn + prow) * K + ((c ^ (row & 7)) << 3);
        ldB[i] = cid << 4;
    }

    int nt = K >> 6;
#pragma unroll
    for (int i = 0; i < 2; ++i) gld16(smem + ldA[i], Ap[i]);
#pragma unroll
    for (int i = 0; i < 4; ++i) gld16(smem + 8192 + ldB[i], Bp[i]);
    __syncthreads();

    for (int tk = 0; tk < nt; ++tk) {
        int cur = (tk & 1) * 24576;
        if (tk + 1 < nt) {
            int k0 = (tk + 1) << 6;
            int nxt = 24576 - cur;
#pragma unroll
            for (int i = 0; i < 2; ++i) gld16(smem + nxt + ldA[i], Ap[i] + k0);
#pragma unroll
            for (int i = 0; i < 4; ++i) gld16(smem + nxt + 8192 + ldB[i], Bp[i] + k0);
        }
        const unsigned short* sA = (const unsigned short*)(smem + cur);
        const unsigned short* sB = (const unsigned short*)(smem + cur + 8192);
#pragma unroll
        for (int kk = 0; kk < 2; ++kk) {
            bf16x8 af[4], bv[2];
#pragma unroll
            for (int mi = 0; mi < 4; ++mi)
                af[mi] = *(const bf16x8*)(sA + SWZ(mi * 16 + lrow, kk * 4 + kq));
#pragma unroll
            for (int ni = 0; ni < 2; ++ni)
                bv[ni] = *(const bf16x8*)(sB + SWZ(w * 32 + ni * 16 + lrow, kk * 4 + kq));
#pragma unroll
            for (int mi = 0; mi < 4; ++mi)
#pragma unroll
                for (int ni = 0; ni < 2; ++ni)
                    acc[mi][ni] = __builtin_amdgcn_mfma_f32_16x16x32_bf16(af[mi], bv[ni], acc[mi][ni], 0, 0, 0);
        }
        __syncthreads();
    }

    int crow = (l >> 4) * 4;
    int ccol = l & 15;
    int gcolb = bn + w * 32 + ccol * 2;   // 2 contiguous output columns
    float2 b2 = *(const float2*)(bias + gcolb);
#pragma unroll
    for (int mi = 0; mi < 4; ++mi) {
#pragma unroll
        for (int r = 0; r < 4; ++r) {
            int grow = bm + mi * 16 + crow + r;
            size_t off = (size_t)grow * N + gcolb;
            float v0 = acc[mi][0][r] + b2.x;
            float v1 = acc[mi][1][r] + b2.y;
            if (EPI == 1) {
                float2 rr = *(const float2*)(resid + off);
                float2 o2 = {v0 + rr.x, v1 + rr.y};
                *(float2*)(Cf + off) = o2;
            } else {
                if (EPI == 2) { v0 = gelu_f(v0); v1 = gelu_f(v1); }
                *(unsigned*)(Cb + off) = pk2bf(v0, v1);
            }
        }
    }
}

// ---------------- MFMA flash attention v4: 128 q-rows / 8 waves per block ----------------
// NEW vs v3: XCD pair-locality block remap.  Default dispatch spreads the 16
// q-tile blocks sharing one head's 512KB K/V stream across all 8 XCDs ->
// every XCD refetches (nearly) every head's KV through its private L2
// (measured FETCH 70MB vs 24MB unique input).  Remap: XCD x (= hwid & 7) owns
// (head,batch) pairs [4x, 4x+4); its 64 resident blocks are those pairs'
// 16 q-tiles.  Bijective (8x64 <-> 32x16).  Per-XCD KV working set = 4 x 512KB
// = 2MB -> L2-resident; each KV stream fetched from HBM by exactly one XCD.
__global__ __launch_bounds__(512) void mattn(const unsigned short* __restrict__ qkv,
                                             unsigned short* __restrict__ out)
{
    __shared__ unsigned short Qs[128 * 64];       // [q][d] swizzled (16KB)
    __shared__ unsigned short Ks[2][64 * 64];     // [k][d] swizzled, dbuf (16KB)
    __shared__ unsigned short Vt[2][64 * 64];     // [d][k] swizzled, dbuf (16KB)
    __shared__ unsigned short Ps[8 * 16 * 64];    // per-wave [q16][k64] swizzled (16KB)
    int t = threadIdx.x;
    int w = t >> 6, l = t & 63;
    int lr = l & 15, lh = l >> 4;
    // XCD pair-locality remap (grid = 16 x 16 x 2 = 512 blocks, all co-resident)
    int hwid = blockIdx.x + (blockIdx.y << 4) + (blockIdx.z << 8);
    int xcd = hwid & 7, slot = hwid >> 3;
    int pair = (xcd << 2) + (slot >> 4);
    int q0 = (slot & 15) * 128;
    int hh = pair & 15, b = pair >> 4;
    const unsigned short* Qg = qkv + (size_t)b * SEQ * 3072 + hh * 64;
    const unsigned short* Kg = Qg + 1024;
    const unsigned short* Vg = Qg + 2048;

    // ---- stage Q via gld16 (pre-swizzled global source): 1024 chunks, 2/thread ----
#pragma unroll
    for (int i = 0; i < 2; ++i) {
        int chunkid = i * 512 + t;
        int row = chunkid >> 3, c = chunkid & 7;
        gld16(((char*)Qs) + chunkid * 16,
              Qg + (size_t)(q0 + row) * 3072 + ((c ^ (row & 7)) << 3));
    }

    // ---- K reg-staging: 512 chunks (64 rows x 8), 1 per thread ----
    int kr0 = t >> 3, kc0 = t & 7;
    const unsigned short* Kp0 = Kg + (size_t)kr0 * 3072 + kc0 * 8;
    int kd0 = SWZ(kr0, kc0);
    // ---- V: thread handles k-pair (vk,vk+1) x 4 d-elems ----
    int vk = (t & 31) * 2;
    int vd0 = ((t >> 5) & 15) * 4;
    const unsigned short* Vp0 = Vg + (size_t)vk * 3072 + vd0;
    const unsigned short* Vp1 = Vp0 + 3072;

    // prologue: load K/V tile 0 to regs
    u16x8 k0 = *(const u16x8*)Kp0;
    u16x4 v0 = *(const u16x4*)Vp0;
    u16x4 v1 = *(const u16x4*)Vp1;
    Kp0 += 64 * 3072; Vp0 += 64 * 3072; Vp1 += 64 * 3072;

    __syncthreads();   // Qs ready (full drain; prologue only)
    bf16x8 qa[2];
#pragma unroll
    for (int ks = 0; ks < 2; ++ks)
        qa[ks] = *(const bf16x8*)(Qs + SWZ(w * 16 + lr, ks * 4 + lh));

    // write tile 0 into buffer 0
    *(u16x8*)(Ks[0] + kd0) = k0;
#pragma unroll
    for (int j = 0; j < 4; ++j) {
        int d = vd0 + j;
        unsigned pack = (unsigned)(unsigned short)v0[j] | ((unsigned)(unsigned short)v1[j] << 16);
        *(unsigned*)(Vt[0] + SWZ(d, vk >> 3) + (vk & 7)) = pack;
    }
    // prefetch tile 1 to regs (stays in flight across the raw barrier)
    k0 = *(const u16x8*)Kp0;
    v0 = *(const u16x4*)Vp0; v1 = *(const u16x4*)Vp1;
    Kp0 += 64 * 3072; Vp0 += 64 * 3072; Vp1 += 64 * 3072;
    asm volatile("s_waitcnt lgkmcnt(0)" ::: "memory");   // publish buf0 writes
    __builtin_amdgcn_s_barrier();

    f32x4 o[4];
#pragma unroll
    for (int i = 0; i < 4; ++i) o[i] = {0.f, 0.f, 0.f, 0.f};
    float mr = -3.0e38f, lsum = 0.f;   // per-lane: q-row = w*16 + lr
    unsigned short* Pw = Ps + w * (16 * 64);
    const float C = 0.18033688011112042f;  // 0.125 * log2(e)

    const int nt = SEQ / 64;   // 32
    for (int tt = 0; tt < nt; ++tt) {
        const unsigned short* Kc = Ks[tt & 1];
        const unsigned short* Vc = Vt[tt & 1];

        // swapped QK^T: S^T = K·Q^T -> lane holds q=lr, k=ni*16+lh*4+r
        f32x4 s[4];
#pragma unroll
        for (int ni = 0; ni < 4; ++ni) s[ni] = {0.f, 0.f, 0.f, 0.f};
#pragma unroll
        for (int ks = 0; ks < 2; ++ks) {
#pragma unroll
            for (int ni = 0; ni < 4; ++ni) {
                bf16x8 kb = *(const bf16x8*)(Kc + SWZ(ni * 16 + lr, ks * 4 + lh));
                s[ni] = __builtin_amdgcn_mfma_f32_16x16x32_bf16(kb, qa[ks], s[ni], 0, 0, 0);
            }
        }
        // row max: 15 in-reg + 2 shfl (lanes sharing lr)
        float mx = s[0][0];
#pragma unroll
        for (int ni = 0; ni < 4; ++ni)
#pragma unroll
            for (int r = 0; r < 4; ++r) mx = fmaxf(mx, s[ni][r]);
        mx = fmaxf(mx, __shfl_xor(mx, 16));
        mx = fmaxf(mx, __shfl_xor(mx, 32));
        // defer-max: only rescale when growth beyond e^8 bound (always on tile 0)
        if (__any(mx > mr + 64.0f)) {
            float mn = fmaxf(mr, mx);
            float corr = fexp2((mr - mn) * C);
            mr = mn;
            lsum *= corr;
            float cr[4];
#pragma unroll
            for (int r = 0; r < 4; ++r) cr[r] = __shfl(corr, lh * 4 + r, 16);
#pragma unroll
            for (int nd = 0; nd < 4; ++nd) {
                o[nd][0] *= cr[0]; o[nd][1] *= cr[1];
                o[nd][2] *= cr[2]; o[nd][3] *= cr[3];
            }
        }
        float mc = mr * C;
        float rsum = 0.f;
#pragma unroll
        for (int ni = 0; ni < 4; ++ni)
#pragma unroll
            for (int r = 0; r < 4; ++r) {
                float p = fexp2(fmaf(s[ni][r], C, -mc));
                s[ni][r] = p;
                rsum += p;
            }
        rsum += __shfl_xor(rsum, 16);
        rsum += __shfl_xor(rsum, 32);
        lsum += rsum;
        // P write: packed pairs (adjacent k = r, r+1)
#pragma unroll
        for (int ni = 0; ni < 4; ++ni)
#pragma unroll
            for (int rp = 0; rp < 2; ++rp) {
                int k = ni * 16 + lh * 4 + rp * 2;
                *(unsigned*)(Pw + SWZ(lr, k >> 3) + (k & 7)) =
                    pk2bf(s[ni][rp * 2], s[ni][rp * 2 + 1]);
            }
        // PV: O[q16][d64] += P[q16][k64] @ V[k64][d64]
#pragma unroll
        for (int ks = 0; ks < 2; ++ks) {
            bf16x8 pa = *(const bf16x8*)(Pw + SWZ(lr, ks * 4 + lh));
#pragma unroll
            for (int nd = 0; nd < 4; ++nd) {
                bf16x8 vb = *(const bf16x8*)(Vc + SWZ(nd * 16 + lr, ks * 4 + lh));
                o[nd] = __builtin_amdgcn_mfma_f32_16x16x32_bf16(pa, vb, o[nd], 0, 0, 0);
            }
        }

        // ---- post-compute: write next tile's K/V (regs -> LDS), prefetch t+2 ----
        if (tt + 1 < nt) {
            int nb = (tt & 1) ^ 1;
            // implicit vmcnt wait here covers loads issued one full tile ago
            *(u16x8*)(Ks[nb] + kd0) = k0;
#pragma unroll
            for (int j = 0; j < 4; ++j) {
                int d = vd0 + j;
                unsigned pack = (unsigned)(unsigned short)v0[j] | ((unsigned)(unsigned short)v1[j] << 16);
                *(unsigned*)(Vt[nb] + SWZ(d, vk >> 3) + (vk & 7)) = pack;
            }
            if (tt + 2 < nt) {
                k0 = *(const u16x8*)Kp0;
                v0 = *(const u16x4*)Vp0; v1 = *(const u16x4*)Vp1;
                Kp0 += 64 * 3072; Vp0 += 64 * 3072; Vp1 += 64 * 3072;
            }
            asm volatile("s_waitcnt lgkmcnt(0)" ::: "memory");  // publish nb writes
            __builtin_amdgcn_s_barrier();                        // raw: no vmcnt drain
        }
    }
    // epilogue: redistribute 1/lsum to PV row owners
    float inv = 1.0f / lsum;
    float ir[4];
#pragma unroll
    for (int r = 0; r < 4; ++r) ir[r] = __shfl(inv, lh * 4 + r, 16);
#pragma unroll
    for (int r = 0; r < 4; ++r) {
        int q = q0 + w * 16 + lh * 4 + r;
#pragma unroll
        for (int nd = 0; nd < 4; ++nd) {
            int d = nd * 16 + lr;
            out[(size_t)((size_t)b * SEQ + q) * HDIM + hh * 64 + d] = f2bf(o[nd][r] * ir[r]);
        }
    }
}

extern "C" void kernel_launch(void* const* d_in, const int* in_sizes, int n_in,
                              void* d_out, int out_size, void* d_ws, size_t ws_size,
                              hipStream_t stream)
{
    const float* x     = (const float*)d_in[0];
    const float* ln1_g = (const float*)d_in[1];
    const float* ln1_b = (const float*)d_in[2];
    const float* W_qkv = (const float*)d_in[3];
    const float* b_qkv = (const float*)d_in[4];
    const float* W_out = (const float*)d_in[5];
    const float* b_out = (const float*)d_in[6];
    const float* ln2_g = (const float*)d_in[7];
    const float* ln2_b = (const float*)d_in[8];
    const float* W1    = (const float*)d_in[9];
    const float* b1    = (const float*)d_in[10];
    const float* W2    = (const float*)d_in[11];
    const float* b2    = (const float*)d_in[12];
    float* out = (float*)d_out;
    char* ws8  = (char*)d_ws;

    const int M = BATCH * SEQ;  // 4096
    const size_t MB = 1048576;

    unsigned short* hbuf = (unsigned short*)(ws8);
    unsigned short* qkvb = (unsigned short*)(ws8 + 8 * MB);
    unsigned short* attb = (unsigned short*)(ws8 + 32 * MB);
    unsigned short* ffn1 = (unsigned short*)(ws8 + 8 * MB);
    unsigned short* WqT  = (unsigned short*)(ws8 + 40 * MB);
    unsigned short* WoT  = (unsigned short*)(ws8 + 46 * MB);
    unsigned short* W1T  = (unsigned short*)(ws8 + 48 * MB);
    unsigned short* W2T  = (unsigned short*)(ws8 + 56 * MB);

    // all 4 weight conversions in one launch (12288 blocks)
    wconv_all<<<12288, 256, 0, stream>>>(W_qkv, W_out, W1, W2, WqT, WoT, W1T, W2T);

    ln_kernel<<<M, 256, 0, stream>>>(x, ln1_g, ln1_b, hbuf);
    // QKV: 128x128, grid 24x32 = 768 blocks
    mgemm<0><<<dim3(3 * HDIM / 128, M / 128), 256, 0, stream>>>(hbuf, WqT, b_qkv, nullptr, nullptr, qkvb, M, 3 * HDIM, HDIM);
    mattn<<<dim3(SEQ / 128, NHEAD, BATCH), 512, 0, stream>>>(qkvb, attb);
    // out-proj: 64x128, grid 8x64 = 512 blocks (2/CU), fused residual
    mgemm64<1><<<dim3(HDIM / 128, M / 64), 256, 0, stream>>>(attb, WoT, b_out, x, out, nullptr, M, HDIM, HDIM);
    ln_kernel<<<M, 256, 0, stream>>>(out, ln2_g, ln2_b, hbuf);
    // FFN1: 128x128, grid 32x32 = 1024 blocks, fused gelu
    mgemm<2><<<dim3(4 * HDIM / 128, M / 128), 256, 0, stream>>>(hbuf, W1T, b1, nullptr, nullptr, ffn1, M, 4 * HDIM, HDIM);
    // FFN2: 64x128, grid 8x64 = 512 blocks (2/CU), fused residual (in-place on out)
    mgemm64<1><<<dim3(HDIM / 128, M / 64), 256, 0, stream>>>(ffn1, W2T, b2, out, out, nullptr, M, HDIM, 4 * HDIM);
}